// Round 2
// baseline (1002.871 us; speedup 1.0000x reference)
//
#include <hip/hip_runtime.h>

#define NSTAT 32
#define TILE_K 32

__device__ __forceinline__ unsigned fkey(float f) {
    unsigned u = __float_as_uint(f);
    return (u & 0x80000000u) ? ~u : (u | 0x80000000u);
}
__device__ __forceinline__ float finv(unsigned u) {
    unsigned b = (u & 0x80000000u) ? (u ^ 0x80000000u) : ~u;
    return __uint_as_float(b);
}

// ---------------- fp32 GEMM core: C128x128 = A[128, 1024] * W[128,1024]^T ----------------
__device__ __forceinline__ void gemm128_core(
    const float* __restrict__ A, const float* __restrict__ W,
    int arow0, int wrow0, int t,
    float (*__restrict__ As)[132], float (*__restrict__ Bs)[132],
    float acc[8][8])
{
    const int tx = t & 15, ty = t >> 4;
    #pragma unroll
    for (int i = 0; i < 8; ++i)
        #pragma unroll
        for (int j = 0; j < 8; ++j) acc[i][j] = 0.f;

    for (int k0 = 0; k0 < 1024; k0 += TILE_K) {
        #pragma unroll
        for (int s = 0; s < 4; ++s) {
            int f = t + s * 256;        // 0..1023
            int row = f >> 3;           // 0..127
            int kq = f & 7;             // 0..7
            const float4 av = *(const float4*)(A + (size_t)(arow0 + row) * 1024 + k0 + kq * 4);
            const float4 wv = *(const float4*)(W + (size_t)(wrow0 + row) * 1024 + k0 + kq * 4);
            As[kq*4+0][row] = av.x; As[kq*4+1][row] = av.y;
            As[kq*4+2][row] = av.z; As[kq*4+3][row] = av.w;
            Bs[kq*4+0][row] = wv.x; Bs[kq*4+1][row] = wv.y;
            Bs[kq*4+2][row] = wv.z; Bs[kq*4+3][row] = wv.w;
        }
        __syncthreads();
        #pragma unroll
        for (int kk = 0; kk < TILE_K; ++kk) {
            float4 a0 = *(const float4*)&As[kk][ty*4];
            float4 a1 = *(const float4*)&As[kk][64 + ty*4];
            float4 b0 = *(const float4*)&Bs[kk][tx*4];
            float4 b1 = *(const float4*)&Bs[kk][64 + tx*4];
            float a[8] = {a0.x, a0.y, a0.z, a0.w, a1.x, a1.y, a1.z, a1.w};
            float b[8] = {b0.x, b0.y, b0.z, b0.w, b1.x, b1.y, b1.z, b1.w};
            #pragma unroll
            for (int i = 0; i < 8; ++i)
                #pragma unroll
                for (int j = 0; j < 8; ++j)
                    acc[i][j] = fmaf(a[i], b[j], acc[i][j]);
        }
        __syncthreads();
    }
}

// QKV projection: rows = b*1024+n, cols select (Wq|Wk|Wv); scatter to [B,H,N,HD]; static-K substitution.
__global__ __launch_bounds__(256)
void gemm_qkv_kernel(const float* __restrict__ x,
                     const float* __restrict__ Wq, const float* __restrict__ bq,
                     const float* __restrict__ Wk, const float* __restrict__ bk,
                     const float* __restrict__ Wv, const float* __restrict__ bv,
                     const float* __restrict__ statk,
                     float* __restrict__ Qo, float* __restrict__ Ko, float* __restrict__ Vo)
{
    __shared__ __align__(16) float As[TILE_K][132];
    __shared__ __align__(16) float Bs[TILE_K][132];
    const int t = threadIdx.x;
    const int bx = blockIdx.x, by = blockIdx.y;   // bx 0..23, by 0..31
    const int which = bx >> 3;
    const int wc0 = (bx & 7) * 128;
    const float* W    = (which == 0) ? Wq : (which == 1) ? Wk : Wv;
    const float* bias = (which == 0) ? bq : (which == 1) ? bk : bv;
    float* Out        = (which == 0) ? Qo : (which == 1) ? Ko : Vo;

    float acc[8][8];
    gemm128_core(x, W, by * 128, wc0, t, As, Bs, acc);

    const int tx = t & 15, ty = t >> 4;
    #pragma unroll
    for (int i = 0; i < 8; ++i) {
        int rl = (i < 4) ? (ty*4 + i) : (64 + ty*4 + (i - 4));
        int r = by * 128 + rl;
        int b = r >> 10, n = r & 1023;
        #pragma unroll
        for (int jq = 0; jq < 2; ++jq) {
            int cl = jq * 64 + tx * 4;
            int c = wc0 + cl;
            float4 v;
            v.x = acc[i][jq*4+0] + bias[c+0];
            v.y = acc[i][jq*4+1] + bias[c+1];
            v.z = acc[i][jq*4+2] + bias[c+2];
            v.w = acc[i][jq*4+3] + bias[c+3];
            if (which == 1 && n < NSTAT) {
                v.x = statk[n*1024 + c + 0];
                v.y = statk[n*1024 + c + 1];
                v.z = statk[n*1024 + c + 2];
                v.w = statk[n*1024 + c + 3];
            }
            int h = c >> 6, d = c & 63;
            *(float4*)(Out + (((size_t)(b*16 + h) * 1024 + n) * 64 + d)) = v;
        }
    }
}

// Output projection: C[4096,1024] = A @ Wo^T + bo, plain row-major store.
__global__ __launch_bounds__(256)
void gemm_out_kernel(const float* __restrict__ A,
                     const float* __restrict__ Wo, const float* __restrict__ bo,
                     float* __restrict__ C)
{
    __shared__ __align__(16) float As[TILE_K][132];
    __shared__ __align__(16) float Bs[TILE_K][132];
    const int t = threadIdx.x;
    const int bx = blockIdx.x, by = blockIdx.y;   // bx 0..7, by 0..31
    const int wc0 = bx * 128;

    float acc[8][8];
    gemm128_core(A, Wo, by * 128, wc0, t, As, Bs, acc);

    const int tx = t & 15, ty = t >> 4;
    #pragma unroll
    for (int i = 0; i < 8; ++i) {
        int rl = (i < 4) ? (ty*4 + i) : (64 + ty*4 + (i - 4));
        int r = by * 128 + rl;
        #pragma unroll
        for (int jq = 0; jq < 2; ++jq) {
            int cl = jq * 64 + tx * 4;
            int c = wc0 + cl;
            float4 v;
            v.x = acc[i][jq*4+0] + bo[c+0];
            v.y = acc[i][jq*4+1] + bo[c+1];
            v.z = acc[i][jq*4+2] + bo[c+2];
            v.w = acc[i][jq*4+3] + bo[c+3];
            *(float4*)(C + (size_t)r * 1024 + c) = v;
        }
    }
}

// ---------------- fused scores + exact top-64 (with boundary hedge) + softmax + PV ----------------
// block = (b, h, 16-query tile); 256 threads.
// score layout for top-k: thread (r = t>>4, l = t&15) owns keys [l*64, l*64+64) of query row r.
#define MAXSEL 80

__global__ __launch_bounds__(256)
void attn_kernel(const float* __restrict__ Qw, const float* __restrict__ Kw,
                 const float* __restrict__ Vw, float* __restrict__ outp)
{
    __shared__ __align__(16) float Qs[16][64];
    __shared__ __align__(16) float Ks[128 * 64];     // quad-swizzled
    __shared__ float rbuf[16][132];
    __shared__ int   selm[16][MAXSEL];
    __shared__ float selw[16][MAXSEL];
    __shared__ float rowsum[16];
    __shared__ int   rowcnt[16];

    const int t = threadIdx.x;
    const int bid = blockIdx.x;          // ((b*16+h)*64 + qt)
    const int qt = bid & 63;
    const int bh = bid >> 6;             // b*16+h
    const int n0 = qt * 16;
    const float* Qbase = Qw + ((size_t)bh * 1024 + n0) * 64;
    const float* Kbase = Kw + (size_t)bh * 1024 * 64;
    const float* Vbase = Vw + (size_t)bh * 1024 * 64;

    const int r = t >> 4, l = t & 15;    // top-k layout
    const int ty = t >> 6, tx = t & 63;  // score-compute layout

    // stage Q tile
    {
        int q = t >> 4, dq = (t & 15) * 4;
        *(float4*)&Qs[q][dq] = *(const float4*)(Qbase + q * 64 + dq);
    }

    unsigned su[64];                     // this lane's 64 score keys

    for (int c = 0; c < 8; ++c) {
        // stage K chunk (128 keys x 64 dims), quad-swizzled rows
        #pragma unroll
        for (int s = 0; s < 8; ++s) {
            int f = t + s * 256;         // 0..2047 quads
            int row = f >> 4, cq = f & 15;
            float4 v = *(const float4*)(Kbase + ((size_t)(c * 128 + row)) * 64 + cq * 4);
            ((float4*)Ks)[row * 16 + (cq ^ (row & 7))] = v;
        }
        __syncthreads();

        // compute 4q x 2m scores per thread
        float accs[4][2];
        #pragma unroll
        for (int i = 0; i < 4; ++i) { accs[i][0] = 0.f; accs[i][1] = 0.f; }
        #pragma unroll
        for (int dq = 0; dq < 16; ++dq) {
            float4 k0 = ((const float4*)Ks)[tx * 16 + (dq ^ (tx & 7))];
            float4 k1 = ((const float4*)Ks)[(tx + 64) * 16 + (dq ^ (tx & 7))];
            #pragma unroll
            for (int i = 0; i < 4; ++i) {
                float4 qv = *(const float4*)&Qs[ty * 4 + i][dq * 4];
                accs[i][0] += qv.x*k0.x + qv.y*k0.y + qv.z*k0.z + qv.w*k0.w;
                accs[i][1] += qv.x*k1.x + qv.y*k1.y + qv.z*k1.z + qv.w*k1.w;
            }
        }
        #pragma unroll
        for (int i = 0; i < 4; ++i) {
            rbuf[ty*4 + i][tx]      = accs[i][0];
            rbuf[ty*4 + i][tx + 64] = accs[i][1];
        }
        __syncthreads();

        // owner lanes pull their contiguous 64-key segment into registers
        if ((l >> 1) == c) {
            #pragma unroll
            for (int j = 0; j < 64; ++j)
                su[j] = fkey(rbuf[r][(l & 1) * 64 + j]);
        }
        // (next iteration's first __syncthreads orders rbuf reuse)
    }

    // ---- exact 64-th largest per row via 32-bit radix binary search ----
    unsigned v = 0;
    #pragma unroll 1
    for (int bit = 31; bit >= 0; --bit) {
        unsigned cand = v | (1u << bit);
        int cnt = 0;
        #pragma unroll
        for (int j = 0; j < 64; ++j) cnt += (su[j] >= cand) ? 1 : 0;
        #pragma unroll
        for (int off = 8; off; off >>= 1) cnt += __shfl_xor(cnt, off, 16);
        if (cnt >= 64) v = cand;
    }

    // row max (for softmax)
    unsigned umax = 0u;
    #pragma unroll
    for (int j = 0; j < 64; ++j) umax = (su[j] > umax) ? su[j] : umax;
    #pragma unroll
    for (int off = 8; off; off >>= 1) {
        unsigned o = __shfl_xor(umax, off, 16);
        umax = (o > umax) ? o : umax;
    }
    const float smax = finv(umax);

    // ---- boundary hedge: keys within +-DELTA of the 64th score get fractional weight ----
    const float sthr = finv(v);
    const float DELTA = 2e-5f;
    const float hi = sthr + DELTA, lo = sthr - DELTA;

    int cdef = 0, cbnd = 0;
    #pragma unroll
    for (int j = 0; j < 64; ++j) {
        float s = finv(su[j]);
        cdef += (s > hi) ? 1 : 0;
        cbnd += (s >= lo && s <= hi) ? 1 : 0;
    }
    int gi = cdef, ei = cbnd;
    #pragma unroll
    for (int off = 1; off < 16; off <<= 1) {
        int g = __shfl_up(gi, off, 16);
        int e = __shfl_up(ei, off, 16);
        if (l >= off) { gi += g; ei += e; }
    }
    const int def_excl = gi - cdef, bnd_excl = ei - cbnd;
    const int D_tot = __shfl(gi, 15, 16);
    const int m_tot = __shfl(ei, 15, 16);
    const int j_need = 64 - D_tot;               // boundary slots the reference fills
    const float frac = (float)j_need / (float)m_tot;

    float lsum = 0.f;
    int dpos = def_excl, bpos = bnd_excl;
    #pragma unroll
    for (int j = 0; j < 64; ++j) {
        float s = finv(su[j]);
        int slot = -1; float w = 0.f;
        if (s > hi) {
            slot = dpos++;
            w = __expf((s - smax) * 0.125f);
        } else if (s >= lo) {
            slot = D_tot + bpos++;
            w = __expf((s - smax) * 0.125f) * frac;
        }
        if (slot >= 0 && slot < MAXSEL) {
            selm[r][slot] = l * 64 + j;
            selw[r][slot] = w;
            lsum += w;
        }
    }
    #pragma unroll
    for (int off = 8; off; off >>= 1) lsum += __shfl_xor(lsum, off, 16);
    if (l == 0) {
        rowsum[r] = lsum;
        int ct = D_tot + m_tot;
        rowcnt[r] = (ct > MAXSEL) ? MAXSEL : ct;
    }
    __syncthreads();

    // ---- PV: out[q][d] = sum_j w_j * V[m_j][d] / rowsum ----
    {
        const int d = t & 63, qg = t >> 6;
        const int b = bh >> 4, h = bh & 15;
        #pragma unroll
        for (int i = 0; i < 4; ++i) {
            int q = qg * 4 + i;
            int cend = rowcnt[q];
            float a = 0.f;
            for (int j = 0; j < cend; ++j)
                a += selw[q][j] * Vbase[(size_t)selm[q][j] * 64 + d];
            outp[((size_t)b * 1024 + (n0 + q)) * 1024 + h * 64 + d] = a / rowsum[q];
        }
    }
}

extern "C" void kernel_launch(void* const* d_in, const int* in_sizes, int n_in,
                              void* d_out, int out_size, void* d_ws, size_t ws_size,
                              hipStream_t stream) {
    const float* x     = (const float*)d_in[0];
    const float* Wq    = (const float*)d_in[1];
    const float* bq    = (const float*)d_in[2];
    const float* Wk    = (const float*)d_in[3];
    const float* bk    = (const float*)d_in[4];
    const float* Wv    = (const float*)d_in[5];
    const float* bv    = (const float*)d_in[6];
    const float* Wo    = (const float*)d_in[7];
    const float* bo    = (const float*)d_in[8];
    const float* statk = (const float*)d_in[9];
    float* out = (float*)d_out;
    float* ws  = (float*)d_ws;

    float* Qw = ws;                      // 4M floats each
    float* Kw = ws + (size_t)(1 << 22);
    float* Vw = ws + (size_t)(2 << 22);
    float* op = ws + (size_t)(3 << 22);

    dim3 g1(24, 32);
    gemm_qkv_kernel<<<g1, 256, 0, stream>>>(x, Wq, bq, Wk, bk, Wv, bv, statk, Qw, Kw, Vw);
    attn_kernel<<<4096, 256, 0, stream>>>(Qw, Kw, Vw, op);
    dim3 g2(8, 32);
    gemm_out_kernel<<<g2, 256, 0, stream>>>(op, Wo, bo, out);
}

// Round 3
// 848.480 us; speedup vs baseline: 1.1820x; 1.1820x over previous
//
#include <hip/hip_runtime.h>

#define NSTAT 32
#define TILE_K 32
#define MAXSEL 80

typedef __attribute__((ext_vector_type(8))) short bf16x8_t;
typedef __attribute__((ext_vector_type(4))) float f32x4_t;

__device__ __forceinline__ unsigned fkey(float f) {
    unsigned u = __float_as_uint(f);
    return (u & 0x80000000u) ? ~u : (u | 0x80000000u);
}
__device__ __forceinline__ float finv(unsigned u) {
    unsigned b = (u & 0x80000000u) ? (u ^ 0x80000000u) : ~u;
    return __uint_as_float(b);
}

// Exact 3-limb bf16 decomposition of f32 (truncation limbs; hi+mid+lo == a exactly)
__device__ __forceinline__ void limb3(float a, ushort& h, ushort& m, ushort& l) {
    unsigned u = __float_as_uint(a);
    unsigned uh = u & 0xFFFF0000u;
    float fh = __uint_as_float(uh);
    float r1 = a - fh;                       // exact (low 16 bits of significand)
    unsigned u1 = __float_as_uint(r1);
    unsigned um = u1 & 0xFFFF0000u;
    float fm = __uint_as_float(um);
    float r2 = r1 - fm;                      // exact (<=8 sig bits)
    h = (ushort)(uh >> 16);
    m = (ushort)(um >> 16);
    l = (ushort)(__float_as_uint(r2) >> 16); // exact truncation
}

#define COUNT_GE16(thr, out) do { \
    int _c = 0; \
    _Pragma("unroll") \
    for (int _j = 0; _j < 64; ++_j) _c += (su[_j] >= (thr)) ? 1 : 0; \
    _Pragma("unroll") \
    for (int _o = 8; _o; _o >>= 1) _c += __shfl_xor(_c, _o, 16); \
    (out) = _c; \
} while (0)

// ---------------- fp32 GEMM core: C128x128 = A[128, 1024] * W[128,1024]^T ----------------
__device__ __forceinline__ void gemm128_core(
    const float* __restrict__ A, const float* __restrict__ W,
    int arow0, int wrow0, int t,
    float (*__restrict__ As)[132], float (*__restrict__ Bs)[132],
    float acc[8][8])
{
    const int tx = t & 15, ty = t >> 4;
    #pragma unroll
    for (int i = 0; i < 8; ++i)
        #pragma unroll
        for (int j = 0; j < 8; ++j) acc[i][j] = 0.f;

    for (int k0 = 0; k0 < 1024; k0 += TILE_K) {
        #pragma unroll
        for (int s = 0; s < 4; ++s) {
            int f = t + s * 256;
            int row = f >> 3;
            int kq = f & 7;
            const float4 av = *(const float4*)(A + (size_t)(arow0 + row) * 1024 + k0 + kq * 4);
            const float4 wv = *(const float4*)(W + (size_t)(wrow0 + row) * 1024 + k0 + kq * 4);
            As[kq*4+0][row] = av.x; As[kq*4+1][row] = av.y;
            As[kq*4+2][row] = av.z; As[kq*4+3][row] = av.w;
            Bs[kq*4+0][row] = wv.x; Bs[kq*4+1][row] = wv.y;
            Bs[kq*4+2][row] = wv.z; Bs[kq*4+3][row] = wv.w;
        }
        __syncthreads();
        #pragma unroll
        for (int kk = 0; kk < TILE_K; ++kk) {
            float4 a0 = *(const float4*)&As[kk][ty*4];
            float4 a1 = *(const float4*)&As[kk][64 + ty*4];
            float4 b0 = *(const float4*)&Bs[kk][tx*4];
            float4 b1 = *(const float4*)&Bs[kk][64 + tx*4];
            float a[8] = {a0.x, a0.y, a0.z, a0.w, a1.x, a1.y, a1.z, a1.w};
            float b[8] = {b0.x, b0.y, b0.z, b0.w, b1.x, b1.y, b1.z, b1.w};
            #pragma unroll
            for (int i = 0; i < 8; ++i)
                #pragma unroll
                for (int j = 0; j < 8; ++j)
                    acc[i][j] = fmaf(a[i], b[j], acc[i][j]);
        }
        __syncthreads();
    }
}

// QKV projection. mode==1: K written as pre-swizzled bf16 limb arrays; mode==0: K fp32.
__global__ __launch_bounds__(256)
void gemm_qkv_kernel(const float* __restrict__ x,
                     const float* __restrict__ Wq, const float* __restrict__ bq,
                     const float* __restrict__ Wk, const float* __restrict__ bk,
                     const float* __restrict__ Wv, const float* __restrict__ bv,
                     const float* __restrict__ statk,
                     float* __restrict__ Qo, float* __restrict__ Ko, float* __restrict__ Vo,
                     ushort* __restrict__ KH, ushort* __restrict__ KM, ushort* __restrict__ KL,
                     int mode)
{
    __shared__ __align__(16) float As[TILE_K][132];
    __shared__ __align__(16) float Bs[TILE_K][132];
    const int t = threadIdx.x;
    const int bx = blockIdx.x, by = blockIdx.y;   // bx 0..23, by 0..31
    const int which = bx >> 3;
    const int wc0 = (bx & 7) * 128;
    const float* W    = (which == 0) ? Wq : (which == 1) ? Wk : Wv;
    const float* bias = (which == 0) ? bq : (which == 1) ? bk : bv;

    float acc[8][8];
    gemm128_core(x, W, by * 128, wc0, t, As, Bs, acc);

    const int tx = t & 15, ty = t >> 4;
    #pragma unroll
    for (int i = 0; i < 8; ++i) {
        int rl = (i < 4) ? (ty*4 + i) : (64 + ty*4 + (i - 4));
        int r = by * 128 + rl;
        int b = r >> 10, n = r & 1023;
        #pragma unroll
        for (int jq = 0; jq < 2; ++jq) {
            int cl = jq * 64 + tx * 4;
            int c = wc0 + cl;
            float4 v;
            v.x = acc[i][jq*4+0] + bias[c+0];
            v.y = acc[i][jq*4+1] + bias[c+1];
            v.z = acc[i][jq*4+2] + bias[c+2];
            v.w = acc[i][jq*4+3] + bias[c+3];
            if (which == 1 && n < NSTAT) {
                v.x = statk[n*1024 + c + 0];
                v.y = statk[n*1024 + c + 1];
                v.z = statk[n*1024 + c + 2];
                v.w = statk[n*1024 + c + 3];
            }
            int h = c >> 6, d = c & 63;       // d == tx*4
            size_t bhn = ((size_t)(b*16 + h)) * 1024 + n;
            if (which == 1 && mode == 1) {
                // pre-swizzled limb store: quad' = quad ^ (n&7)
                int qd = tx >> 1;
                int qs = qd ^ (n & 7);
                size_t base = bhn * 64 + (size_t)qs * 8 + (tx & 1) * 4;
                ushort4 sh, sm, sl;
                limb3(v.x, sh.x, sm.x, sl.x);
                limb3(v.y, sh.y, sm.y, sl.y);
                limb3(v.z, sh.z, sm.z, sl.z);
                limb3(v.w, sh.w, sm.w, sl.w);
                *(ushort4*)(KH + base) = sh;
                *(ushort4*)(KM + base) = sm;
                *(ushort4*)(KL + base) = sl;
            } else {
                float* Out = (which == 0) ? Qo : (which == 1) ? Ko : Vo;
                *(float4*)(Out + bhn * 64 + d) = v;
            }
        }
    }
}

// Output projection: C[4096,1024] = A @ Wo^T + bo.
__global__ __launch_bounds__(256)
void gemm_out_kernel(const float* __restrict__ A,
                     const float* __restrict__ Wo, const float* __restrict__ bo,
                     float* __restrict__ C)
{
    __shared__ __align__(16) float As[TILE_K][132];
    __shared__ __align__(16) float Bs[TILE_K][132];
    const int t = threadIdx.x;
    const int bx = blockIdx.x, by = blockIdx.y;
    const int wc0 = bx * 128;

    float acc[8][8];
    gemm128_core(A, Wo, by * 128, wc0, t, As, Bs, acc);

    const int tx = t & 15, ty = t >> 4;
    #pragma unroll
    for (int i = 0; i < 8; ++i) {
        int rl = (i < 4) ? (ty*4 + i) : (64 + ty*4 + (i - 4));
        int r = by * 128 + rl;
        #pragma unroll
        for (int jq = 0; jq < 2; ++jq) {
            int cl = jq * 64 + tx * 4;
            int c = wc0 + cl;
            float4 v;
            v.x = acc[i][jq*4+0] + bo[c+0];
            v.y = acc[i][jq*4+1] + bo[c+1];
            v.z = acc[i][jq*4+2] + bo[c+2];
            v.w = acc[i][jq*4+3] + bo[c+3];
            *(float4*)(C + (size_t)r * 1024 + c) = v;
        }
    }
}

// ---------------- MFMA attn: 3-limb bf16 scores + f32 bisection top-64 hedge + PV ----------------
// block = (b,h,16-query tile); 256 threads / 4 waves.
// topk owner layout: thread (r=t>>4, l=t&15) owns keys [l*64, l*64+64) of query row r.
__global__ __launch_bounds__(256)
void attn_mfma_kernel(const float* __restrict__ Qw,
                      const ushort* __restrict__ KH, const ushort* __restrict__ KM,
                      const ushort* __restrict__ KL,
                      const float* __restrict__ Vw, float* __restrict__ outp)
{
    __shared__ __align__(16) float Qs[16][68];
    __shared__ __align__(16) ushort Klds[3][128 * 64];   // quad-swizzled
    __shared__ __align__(16) float sc[16][132];
    __shared__ uint2 sel[16][MAXSEL];
    __shared__ float rowsum[16];
    __shared__ int   rowcnt[16];

    const int t = threadIdx.x;
    const int bid = blockIdx.x;          // ((b*16+h)*64 + qt)
    const int qt = bid & 63;
    const int bh = bid >> 6;
    const int n0 = qt * 16;
    const float* Qbase = Qw + ((size_t)bh * 1024 + n0) * 64;
    const float* Vbase = Vw + (size_t)bh * 1024 * 64;
    const ushort* KHb = KH + (size_t)bh * 1024 * 64;
    const ushort* KMb = KM + (size_t)bh * 1024 * 64;
    const ushort* KLb = KL + (size_t)bh * 1024 * 64;

    const int ll = t & 63;               // wave lane
    const int w  = t >> 6;               // wave id
    const int r  = t >> 4, l = t & 15;   // topk owner layout

    // stage Q tile
    {
        int q = t >> 4, dq = (t & 15) * 4;
        *(float4*)&Qs[q][dq] = *(const float4*)(Qbase + q * 64 + dq);
    }
    // stage K-limb chunk 0 (linear copy of pre-swizzled global)
    {
        const float4* gh = (const float4*)KHb;
        const float4* gm = (const float4*)KMb;
        const float4* gl = (const float4*)KLb;
        float4* lh = (float4*)Klds[0];
        float4* lm = (float4*)Klds[1];
        float4* lb = (float4*)Klds[2];
        #pragma unroll
        for (int i = 0; i < 4; ++i) {
            lh[t + i*256] = gh[t + i*256];
            lm[t + i*256] = gm[t + i*256];
            lb[t + i*256] = gl[t + i*256];
        }
    }
    __syncthreads();

    // build A fragments (Q limbs) — held in registers for the whole kernel
    bf16x8_t aH[2], aM[2], aL[2];
    {
        const int arow = ll & 15, akg = ll >> 4;
        #pragma unroll
        for (int s = 0; s < 2; ++s) {
            const float* qp = &Qs[arow][s*32 + akg*8];
            float4 q0 = *(const float4*)qp;
            float4 q1 = *(const float4*)(qp + 4);
            float qv[8] = {q0.x,q0.y,q0.z,q0.w,q1.x,q1.y,q1.z,q1.w};
            #pragma unroll
            for (int j = 0; j < 8; ++j) {
                ushort hh, mm, lb2;
                limb3(qv[j], hh, mm, lb2);
                aH[s][j] = (short)hh; aM[s][j] = (short)mm; aL[s][j] = (short)lb2;
            }
        }
    }

    float su[64];                        // this lane's 64 owned scores

    for (int c = 0; c < 8; ++c) {
        // compute: each wave does 2 m-tiles of 16 keys
        #pragma unroll
        for (int tile = 0; tile < 2; ++tile) {
            const int m0 = w*32 + tile*16;
            const int brow = m0 + (ll & 15);
            f32x4_t a_ = {0.f, 0.f, 0.f, 0.f};
            #pragma unroll
            for (int s = 0; s < 2; ++s) {
                int q2 = (s*4 + (ll >> 4)) ^ (brow & 7);
                int off = brow*64 + q2*8;
                bf16x8_t bH = *(const bf16x8_t*)&Klds[0][off];
                bf16x8_t bM = *(const bf16x8_t*)&Klds[1][off];
                bf16x8_t bL = *(const bf16x8_t*)&Klds[2][off];
                a_ = __builtin_amdgcn_mfma_f32_16x16x32_bf16(aH[s], bH, a_, 0, 0, 0);
                a_ = __builtin_amdgcn_mfma_f32_16x16x32_bf16(aH[s], bM, a_, 0, 0, 0);
                a_ = __builtin_amdgcn_mfma_f32_16x16x32_bf16(aM[s], bH, a_, 0, 0, 0);
                a_ = __builtin_amdgcn_mfma_f32_16x16x32_bf16(aM[s], bM, a_, 0, 0, 0);
                a_ = __builtin_amdgcn_mfma_f32_16x16x32_bf16(aH[s], bL, a_, 0, 0, 0);
                a_ = __builtin_amdgcn_mfma_f32_16x16x32_bf16(aL[s], bH, a_, 0, 0, 0);
            }
            // C/D layout: col = lane&15 (key), row = (lane>>4)*4 + reg (query)
            const int qr = (ll >> 4) * 4;
            const int mcol = m0 + (ll & 15);
            sc[qr+0][mcol] = a_[0];
            sc[qr+1][mcol] = a_[1];
            sc[qr+2][mcol] = a_[2];
            sc[qr+3][mcol] = a_[3];
        }
        __syncthreads();

        // owner lanes pull their contiguous 64-key segment
        if ((l >> 1) == c) {
            const int half = l & 1;
            #pragma unroll
            for (int jq = 0; jq < 16; ++jq) {
                float4 v4 = *(const float4*)&sc[r][half*64 + jq*4];
                su[jq*4+0] = v4.x; su[jq*4+1] = v4.y;
                su[jq*4+2] = v4.z; su[jq*4+3] = v4.w;
            }
        }
        // stage next chunk
        if (c < 7) {
            const size_t cb = (size_t)(c + 1) * 128 * 64;
            const float4* gh = (const float4*)(KHb + cb);
            const float4* gm = (const float4*)(KMb + cb);
            const float4* gl = (const float4*)(KLb + cb);
            float4* lh = (float4*)Klds[0];
            float4* lm = (float4*)Klds[1];
            float4* lb = (float4*)Klds[2];
            #pragma unroll
            for (int i = 0; i < 4; ++i) {
                lh[t + i*256] = gh[t + i*256];
                lm[t + i*256] = gm[t + i*256];
                lb[t + i*256] = gl[t + i*256];
            }
        }
        __syncthreads();
    }

    // ---- row max ----
    float smax = su[0];
    #pragma unroll
    for (int j = 1; j < 64; ++j) smax = fmaxf(smax, su[j]);
    #pragma unroll
    for (int off = 8; off; off >>= 1) smax = fmaxf(smax, __shfl_xor(smax, off, 16));

    // ---- 64th-largest via f32 bisection (eps_b ~ 7.6e-6) ----
    float lo = smax - 16.f, hi = smax;
    int cl;
    COUNT_GE16(lo, cl);
    float wfac = 16.f;
    while (__any(cl < 64)) {
        bool need = (cl < 64);
        wfac *= 4.f;
        float nlo = smax - wfac;
        hi = need ? lo : hi;
        lo = need ? nlo : lo;
        COUNT_GE16(lo, cl);
    }
    #pragma unroll 1
    for (int it = 0; it < 21; ++it) {
        float mid = 0.5f * (lo + hi);
        int c1;
        COUNT_GE16(mid, c1);
        bool ge = (c1 >= 64);
        lo = ge ? mid : lo;
        hi = ge ? hi : mid;
    }
    const float sthr = lo;

    // ---- boundary hedge (band +-4e-5 around threshold) ----
    const float bhi = sthr + 4e-5f, blo = sthr - 4e-5f;
    int cdef = 0, cbnd = 0;
    #pragma unroll
    for (int j = 0; j < 64; ++j) {
        float s = su[j];
        cdef += (s > bhi) ? 1 : 0;
        cbnd += (s >= blo && s <= bhi) ? 1 : 0;
    }
    int gi = cdef, ei = cbnd;
    #pragma unroll
    for (int off = 1; off < 16; off <<= 1) {
        int g = __shfl_up(gi, off, 16);
        int e = __shfl_up(ei, off, 16);
        if (l >= off) { gi += g; ei += e; }
    }
    const int def_excl = gi - cdef, bnd_excl = ei - cbnd;
    const int D_tot = __shfl(gi, 15, 16);
    const int m_tot = __shfl(ei, 15, 16);
    const int j_need = 64 - D_tot;
    const float frac = (float)j_need / (float)m_tot;

    float lsum = 0.f;
    int dpos = def_excl, bpos = bnd_excl;
    #pragma unroll
    for (int j = 0; j < 64; ++j) {
        float s = su[j];
        int slot = -1; float wgt = 0.f;
        if (s > bhi) {
            slot = dpos++;
            wgt = __expf((s - smax) * 0.125f);
        } else if (s >= blo) {
            slot = D_tot + (bpos++);
            wgt = __expf((s - smax) * 0.125f) * frac;
        }
        if (slot >= 0 && slot < MAXSEL) {
            sel[r][slot] = make_uint2((unsigned)(l*64 + j), __float_as_uint(wgt));
            lsum += wgt;
        }
    }
    #pragma unroll
    for (int off = 8; off; off >>= 1) lsum += __shfl_xor(lsum, off, 16);
    if (l == 0) {
        rowsum[r] = lsum;
        int ct = D_tot + m_tot;
        rowcnt[r] = (ct > MAXSEL) ? MAXSEL : ct;
    }
    __syncthreads();

    // ---- PV ----
    {
        const int d = t & 63, qg = t >> 6;
        const int bb = bh >> 4, hh = bh & 15;
        #pragma unroll
        for (int i = 0; i < 4; ++i) {
            int q = qg*4 + i;
            int cend = rowcnt[q];
            float a = 0.f;
            for (int j = 0; j < cend; ++j) {
                uint2 p = sel[q][j];
                a += __uint_as_float(p.y) * Vbase[(size_t)p.x * 64 + d];
            }
            outp[((size_t)bb*1024 + (n0 + q)) * 1024 + hh*64 + d] = a / rowsum[q];
        }
    }
}

// ---------------- fallback fp32 attn (round-2 proven path, used if ws too small) ----------------
__global__ __launch_bounds__(256)
void attn_kernel(const float* __restrict__ Qw, const float* __restrict__ Kw,
                 const float* __restrict__ Vw, float* __restrict__ outp)
{
    __shared__ __align__(16) float Qs[16][64];
    __shared__ __align__(16) float Ks[128 * 64];
    __shared__ float rbuf[16][132];
    __shared__ int   selm[16][MAXSEL];
    __shared__ float selw[16][MAXSEL];
    __shared__ float rowsum[16];
    __shared__ int   rowcnt[16];

    const int t = threadIdx.x;
    const int bid = blockIdx.x;
    const int qt = bid & 63;
    const int bh = bid >> 6;
    const int n0 = qt * 16;
    const float* Qbase = Qw + ((size_t)bh * 1024 + n0) * 64;
    const float* Kbase = Kw + (size_t)bh * 1024 * 64;
    const float* Vbase = Vw + (size_t)bh * 1024 * 64;

    const int r = t >> 4, l = t & 15;
    const int ty = t >> 6, tx = t & 63;

    {
        int q = t >> 4, dq = (t & 15) * 4;
        *(float4*)&Qs[q][dq] = *(const float4*)(Qbase + q * 64 + dq);
    }

    unsigned su[64];

    for (int c = 0; c < 8; ++c) {
        #pragma unroll
        for (int s = 0; s < 8; ++s) {
            int f = t + s * 256;
            int row = f >> 4, cq = f & 15;
            float4 v = *(const float4*)(Kbase + ((size_t)(c * 128 + row)) * 64 + cq * 4);
            ((float4*)Ks)[row * 16 + (cq ^ (row & 7))] = v;
        }
        __syncthreads();

        float accs[4][2];
        #pragma unroll
        for (int i = 0; i < 4; ++i) { accs[i][0] = 0.f; accs[i][1] = 0.f; }
        #pragma unroll
        for (int dq = 0; dq < 16; ++dq) {
            float4 k0 = ((const float4*)Ks)[tx * 16 + (dq ^ (tx & 7))];
            float4 k1 = ((const float4*)Ks)[(tx + 64) * 16 + (dq ^ (tx & 7))];
            #pragma unroll
            for (int i = 0; i < 4; ++i) {
                float4 qv = *(const float4*)&Qs[ty * 4 + i][dq * 4];
                accs[i][0] += qv.x*k0.x + qv.y*k0.y + qv.z*k0.z + qv.w*k0.w;
                accs[i][1] += qv.x*k1.x + qv.y*k1.y + qv.z*k1.z + qv.w*k1.w;
            }
        }
        #pragma unroll
        for (int i = 0; i < 4; ++i) {
            rbuf[ty*4 + i][tx]      = accs[i][0];
            rbuf[ty*4 + i][tx + 64] = accs[i][1];
        }
        __syncthreads();

        if ((l >> 1) == c) {
            #pragma unroll
            for (int j = 0; j < 64; ++j)
                su[j] = fkey(rbuf[r][(l & 1) * 64 + j]);
        }
    }

    unsigned v = 0;
    #pragma unroll 1
    for (int bit = 31; bit >= 0; --bit) {
        unsigned cand = v | (1u << bit);
        int cnt = 0;
        #pragma unroll
        for (int j = 0; j < 64; ++j) cnt += (su[j] >= cand) ? 1 : 0;
        #pragma unroll
        for (int off = 8; off; off >>= 1) cnt += __shfl_xor(cnt, off, 16);
        if (cnt >= 64) v = cand;
    }

    unsigned umax = 0u;
    #pragma unroll
    for (int j = 0; j < 64; ++j) umax = (su[j] > umax) ? su[j] : umax;
    #pragma unroll
    for (int off = 8; off; off >>= 1) {
        unsigned o = __shfl_xor(umax, off, 16);
        umax = (o > umax) ? o : umax;
    }
    const float smax = finv(umax);

    const float sthr = finv(v);
    const float DELTA = 2e-5f;
    const float hi = sthr + DELTA, lo = sthr - DELTA;

    int cdef = 0, cbnd = 0;
    #pragma unroll
    for (int j = 0; j < 64; ++j) {
        float s = finv(su[j]);
        cdef += (s > hi) ? 1 : 0;
        cbnd += (s >= lo && s <= hi) ? 1 : 0;
    }
    int gi = cdef, ei = cbnd;
    #pragma unroll
    for (int off = 1; off < 16; off <<= 1) {
        int g = __shfl_up(gi, off, 16);
        int e = __shfl_up(ei, off, 16);
        if (l >= off) { gi += g; ei += e; }
    }
    const int def_excl = gi - cdef, bnd_excl = ei - cbnd;
    const int D_tot = __shfl(gi, 15, 16);
    const int m_tot = __shfl(ei, 15, 16);
    const int j_need = 64 - D_tot;
    const float frac = (float)j_need / (float)m_tot;

    float lsum = 0.f;
    int dpos = def_excl, bpos = bnd_excl;
    #pragma unroll
    for (int j = 0; j < 64; ++j) {
        float s = finv(su[j]);
        int slot = -1; float wq = 0.f;
        if (s > hi) {
            slot = dpos++;
            wq = __expf((s - smax) * 0.125f);
        } else if (s >= lo) {
            slot = D_tot + bpos++;
            wq = __expf((s - smax) * 0.125f) * frac;
        }
        if (slot >= 0 && slot < MAXSEL) {
            selm[r][slot] = l * 64 + j;
            selw[r][slot] = wq;
            lsum += wq;
        }
    }
    #pragma unroll
    for (int off = 8; off; off >>= 1) lsum += __shfl_xor(lsum, off, 16);
    if (l == 0) {
        rowsum[r] = lsum;
        int ct = D_tot + m_tot;
        rowcnt[r] = (ct > MAXSEL) ? MAXSEL : ct;
    }
    __syncthreads();

    {
        const int d = t & 63, qg = t >> 6;
        const int b = bh >> 4, h = bh & 15;
        #pragma unroll
        for (int i = 0; i < 4; ++i) {
            int q = qg * 4 + i;
            int cend = rowcnt[q];
            float a = 0.f;
            for (int j = 0; j < cend; ++j)
                a += selw[q][j] * Vbase[(size_t)selm[q][j] * 64 + d];
            outp[((size_t)b * 1024 + (n0 + q)) * 1024 + h * 64 + d] = a / rowsum[q];
        }
    }
}

extern "C" void kernel_launch(void* const* d_in, const int* in_sizes, int n_in,
                              void* d_out, int out_size, void* d_ws, size_t ws_size,
                              hipStream_t stream) {
    const float* x     = (const float*)d_in[0];
    const float* Wq    = (const float*)d_in[1];
    const float* bq    = (const float*)d_in[2];
    const float* Wk    = (const float*)d_in[3];
    const float* bk    = (const float*)d_in[4];
    const float* Wv    = (const float*)d_in[5];
    const float* bv    = (const float*)d_in[6];
    const float* Wo    = (const float*)d_in[7];
    const float* bo    = (const float*)d_in[8];
    const float* statk = (const float*)d_in[9];
    float* out = (float*)d_out;
    float* ws  = (float*)d_ws;

    const size_t NF = (size_t)1 << 22;          // 4M elements per [64bh][1024][64] array
    const size_t NEED = NF * 4 * 3 + NF * 2 * 3; // 3 f32 arrays + 3 bf16 arrays = 75.5MB

    if (ws_size >= NEED) {
        // limb path: Q | V | op fp32, then KH/KM/KL bf16
        float* Qw = ws;
        float* Vw = ws + NF;
        float* op = ws + 2 * NF;
        ushort* KH = (ushort*)(ws + 3 * NF);
        ushort* KM = KH + NF;
        ushort* KL = KM + NF;

        dim3 g1(24, 32);
        gemm_qkv_kernel<<<g1, 256, 0, stream>>>(x, Wq, bq, Wk, bk, Wv, bv, statk,
                                                Qw, nullptr, Vw, KH, KM, KL, 1);
        attn_mfma_kernel<<<4096, 256, 0, stream>>>(Qw, KH, KM, KL, Vw, op);
        dim3 g2(8, 32);
        gemm_out_kernel<<<g2, 256, 0, stream>>>(op, Wo, bo, out);
    } else {
        // fallback: round-2 proven fp32 path (64MB)
        float* Qw = ws;
        float* Kw = ws + NF;
        float* Vw = ws + 2 * NF;
        float* op = ws + 3 * NF;

        dim3 g1(24, 32);
        gemm_qkv_kernel<<<g1, 256, 0, stream>>>(x, Wq, bq, Wk, bk, Wv, bv, statk,
                                                Qw, Kw, Vw, nullptr, nullptr, nullptr, 0);
        attn_kernel<<<4096, 256, 0, stream>>>(Qw, Kw, Vw, op);
        dim3 g2(8, 32);
        gemm_out_kernel<<<g2, 256, 0, stream>>>(op, Wo, bo, out);
    }
}

// Round 5
// 688.421 us; speedup vs baseline: 1.4568x; 1.2325x over previous
//
#include <hip/hip_runtime.h>

#define NSTAT 32
#define TILE_K 32
#define MAXSEL 76

typedef __attribute__((ext_vector_type(8))) short bf16x8_t;
typedef __attribute__((ext_vector_type(4))) float f32x4_t;

// round-to-nearest-even bf16 (bit trick)
__device__ __forceinline__ ushort rtn_bf16(float a) {
    unsigned u = __float_as_uint(a);
    return (ushort)((u + 0x7FFFu + ((u >> 16) & 1u)) >> 16);
}
// 2-limb RTN decomposition: a ~= hi + lo, residual <= 2^-18|a|
__device__ __forceinline__ void limb2(float a, ushort& h, ushort& l) {
    ushort hh = rtn_bf16(a);
    float fh = __uint_as_float(((unsigned)hh) << 16);
    float r1 = a - fh;          // exact
    l = rtn_bf16(r1);
    h = hh;
}

// ---------------- fp32 GEMM core: C128x128 = A[128,1024] * W[128,1024]^T ----------------
__device__ __forceinline__ void gemm128_core(
    const float* __restrict__ A, const float* __restrict__ W,
    int arow0, int wrow0, int t,
    float (*__restrict__ As)[132], float (*__restrict__ Bs)[132],
    float acc[8][8])
{
    const int tx = t & 15, ty = t >> 4;
    #pragma unroll
    for (int i = 0; i < 8; ++i)
        #pragma unroll
        for (int j = 0; j < 8; ++j) acc[i][j] = 0.f;

    for (int k0 = 0; k0 < 1024; k0 += TILE_K) {
        #pragma unroll
        for (int s = 0; s < 4; ++s) {
            int f = t + s * 256;
            int row = f >> 3;
            int kq = f & 7;
            const float4 av = *(const float4*)(A + (size_t)(arow0 + row) * 1024 + k0 + kq * 4);
            const float4 wv = *(const float4*)(W + (size_t)(wrow0 + row) * 1024 + k0 + kq * 4);
            As[kq*4+0][row] = av.x; As[kq*4+1][row] = av.y;
            As[kq*4+2][row] = av.z; As[kq*4+3][row] = av.w;
            Bs[kq*4+0][row] = wv.x; Bs[kq*4+1][row] = wv.y;
            Bs[kq*4+2][row] = wv.z; Bs[kq*4+3][row] = wv.w;
        }
        __syncthreads();
        #pragma unroll
        for (int kk = 0; kk < TILE_K; ++kk) {
            float4 a0 = *(const float4*)&As[kk][ty*4];
            float4 a1 = *(const float4*)&As[kk][64 + ty*4];
            float4 b0 = *(const float4*)&Bs[kk][tx*4];
            float4 b1 = *(const float4*)&Bs[kk][64 + tx*4];
            float a[8] = {a0.x, a0.y, a0.z, a0.w, a1.x, a1.y, a1.z, a1.w};
            float b[8] = {b0.x, b0.y, b0.z, b0.w, b1.x, b1.y, b1.z, b1.w};
            #pragma unroll
            for (int i = 0; i < 8; ++i)
                #pragma unroll
                for (int j = 0; j < 8; ++j)
                    acc[i][j] = fmaf(a[i], b[j], acc[i][j]);
        }
        __syncthreads();
    }
}

// QKV projection: Q,V f32 [bh][n][64]; K as 2-limb bf16, pre-swizzled quads (quad ^= n&7).
__global__ __launch_bounds__(256)
void gemm_qkv_kernel(const float* __restrict__ x,
                     const float* __restrict__ Wq, const float* __restrict__ bq,
                     const float* __restrict__ Wk, const float* __restrict__ bk,
                     const float* __restrict__ Wv, const float* __restrict__ bv,
                     const float* __restrict__ statk,
                     float* __restrict__ Qo, float* __restrict__ Vo,
                     ushort* __restrict__ KH, ushort* __restrict__ KL)
{
    __shared__ __align__(16) float As[TILE_K][132];
    __shared__ __align__(16) float Bs[TILE_K][132];
    const int t = threadIdx.x;
    const int bx = blockIdx.x, by = blockIdx.y;   // bx 0..23, by 0..31
    const int which = bx >> 3;
    const int wc0 = (bx & 7) * 128;
    const float* W    = (which == 0) ? Wq : (which == 1) ? Wk : Wv;
    const float* bias = (which == 0) ? bq : (which == 1) ? bk : bv;

    float acc[8][8];
    gemm128_core(x, W, by * 128, wc0, t, As, Bs, acc);

    const int tx = t & 15, ty = t >> 4;
    #pragma unroll
    for (int i = 0; i < 8; ++i) {
        int rl = (i < 4) ? (ty*4 + i) : (64 + ty*4 + (i - 4));
        int r = by * 128 + rl;
        int b = r >> 10, n = r & 1023;
        #pragma unroll
        for (int jq = 0; jq < 2; ++jq) {
            int cl = jq * 64 + tx * 4;
            int c = wc0 + cl;
            float4 v;
            v.x = acc[i][jq*4+0] + bias[c+0];
            v.y = acc[i][jq*4+1] + bias[c+1];
            v.z = acc[i][jq*4+2] + bias[c+2];
            v.w = acc[i][jq*4+3] + bias[c+3];
            if (which == 1 && n < NSTAT) {
                v.x = statk[n*1024 + c + 0];
                v.y = statk[n*1024 + c + 1];
                v.z = statk[n*1024 + c + 2];
                v.w = statk[n*1024 + c + 3];
            }
            int h = c >> 6, d = c & 63;       // d == tx*4
            size_t bhn = ((size_t)(b*16 + h)) * 1024 + n;
            if (which == 1) {
                int qd = tx >> 1;             // quad 0..7 within the 64-elem row
                int qs = qd ^ (n & 7);        // pre-swizzle
                size_t base = bhn * 64 + (size_t)qs * 8 + (size_t)(tx & 1) * 4;
                ushort4 sh, sl;
                limb2(v.x, sh.x, sl.x);
                limb2(v.y, sh.y, sl.y);
                limb2(v.z, sh.z, sl.z);
                limb2(v.w, sh.w, sl.w);
                *(ushort4*)(KH + base) = sh;
                *(ushort4*)(KL + base) = sl;
            } else {
                float* Out = (which == 0) ? Qo : Vo;
                *(float4*)(Out + bhn * 64 + d) = v;
            }
        }
    }
}

// Output projection: C[4096,1024] = A @ Wo^T + bo.
__global__ __launch_bounds__(256)
void gemm_out_kernel(const float* __restrict__ A,
                     const float* __restrict__ Wo, const float* __restrict__ bo,
                     float* __restrict__ C)
{
    __shared__ __align__(16) float As[TILE_K][132];
    __shared__ __align__(16) float Bs[TILE_K][132];
    const int t = threadIdx.x;
    const int bx = blockIdx.x, by = blockIdx.y;
    const int wc0 = bx * 128;

    float acc[8][8];
    gemm128_core(A, Wo, by * 128, wc0, t, As, Bs, acc);

    const int tx = t & 15, ty = t >> 4;
    #pragma unroll
    for (int i = 0; i < 8; ++i) {
        int rl = (i < 4) ? (ty*4 + i) : (64 + ty*4 + (i - 4));
        int r = by * 128 + rl;
        #pragma unroll
        for (int jq = 0; jq < 2; ++jq) {
            int cl = jq * 64 + tx * 4;
            int c = wc0 + cl;
            float4 v;
            v.x = acc[i][jq*4+0] + bo[c+0];
            v.y = acc[i][jq*4+1] + bo[c+1];
            v.z = acc[i][jq*4+2] + bo[c+2];
            v.w = acc[i][jq*4+3] + bo[c+3];
            *(float4*)(C + (size_t)r * 1024 + c) = v;
        }
    }
}

// ---------------- radix-select stage (per 16-lane row group) ----------------
// hist: 16 rows x 256 int bins (LDS). Returns via piv[r] = (bin, remaining target).
__device__ __forceinline__ void radix_stage(int* __restrict__ hist, int r, int l,
                                            const unsigned* __restrict__ ku,
                                            unsigned pref, unsigned prefmask,
                                            int shift, int nbins, int tgt,
                                            int2* __restrict__ piv)
{
    const int per = nbins >> 4;
    #pragma unroll
    for (int b = 0; b < 16; ++b)
        if (b < per) hist[r*256 + l*per + b] = 0;
    __syncthreads();
    #pragma unroll
    for (int j = 0; j < 64; ++j) {
        unsigned k = ku[j];
        if ((k & prefmask) == pref)
            atomicAdd(&hist[r*256 + (int)((k >> shift) & (unsigned)(nbins - 1))], 1);
    }
    __syncthreads();
    int seg = 0;
    for (int b = 0; b < per; ++b) seg += hist[r*256 + l*per + b];
    int suf = seg;
    #pragma unroll
    for (int off = 1; off < 16; off <<= 1) {
        int v = __shfl_down(suf, off, 16);
        suf += (l + off < 16) ? v : 0;
    }
    const int above = suf - seg;                  // keys in higher bins
    if (above < tgt && above + seg >= tgt) {
        int c = above;
        for (int b = per - 1; b >= 0; --b) {
            int h = hist[r*256 + l*per + b];
            if (c + h >= tgt) { piv[r] = make_int2(l*per + b, tgt - c); break; }
            c += h;
        }
    }
    __syncthreads();
}

// ---------------- MFMA attn: 2-limb bf16 scores + radix top-64 + hedge + PV ----------------
// block = (b,h,16-query tile); 256 threads / 4 waves.
// topk owner layout: thread (r=t>>4, l=t&15) owns keys [l*64, l*64+64) of query row r.
// Score quantization: ku = floor(s * 2^15) + 2^20, clamp |s|<=31.9 (static-key scores reach ~25).
__global__ __launch_bounds__(256)
void attn_mfma_kernel(const float* __restrict__ Qw,
                      const ushort* __restrict__ KH, const ushort* __restrict__ KL,
                      const float* __restrict__ Vw, float* __restrict__ outp)
{
    __shared__ __align__(16) float Qs[16][68];
    __shared__ __align__(16) unsigned char kpool[2 * 128 * 64 * 2];  // K limbs / hist alias
    __shared__ __align__(16) float sc[16][132];
    __shared__ ushort selm[16][MAXSEL];
    __shared__ __align__(16) float selw[16][MAXSEL];
    __shared__ int2 piv[16];
    __shared__ float rowsum[16];
    __shared__ int   rowcnt[16];

    ushort* Klds0 = (ushort*)kpool;                // [128*64]
    ushort* Klds1 = Klds0 + 128 * 64;
    int* hist = (int*)kpool;                       // 16 rows x 256 bins (16KB), reused after scores

    const int t = threadIdx.x;
    const int bid0 = blockIdx.x;
    const int bid = (bid0 & 7) * 512 + (bid0 >> 3);   // XCD-contiguous chunks
    const int qt = bid & 63;
    const int bh = bid >> 6;
    const int n0 = qt * 16;
    const float* Qbase = Qw + ((size_t)bh * 1024 + n0) * 64;
    const float* Vbase = Vw + (size_t)bh * 1024 * 64;
    const ushort* KHb = KH + (size_t)bh * 1024 * 64;
    const ushort* KLb = KL + (size_t)bh * 1024 * 64;

    const int ll = t & 63;               // wave lane
    const int w  = t >> 6;               // wave id
    const int r  = t >> 4, l = t & 15;   // topk owner layout

    // stage Q tile
    {
        int q = t >> 4, dq = (t & 15) * 4;
        *(float4*)&Qs[q][dq] = *(const float4*)(Qbase + q * 64 + dq);
    }
    // stage K-limb chunk 0 (linear copy of pre-swizzled global)
    {
        const float4* gh = (const float4*)KHb;
        const float4* gl = (const float4*)KLb;
        float4* lh = (float4*)Klds0;
        float4* lo = (float4*)Klds1;
        #pragma unroll
        for (int i = 0; i < 4; ++i) {
            lh[t + i*256] = gh[t + i*256];
            lo[t + i*256] = gl[t + i*256];
        }
    }
    __syncthreads();

    // A fragments (Q 2-limb), in registers for the whole kernel
    bf16x8_t aH[2], aL[2];
    {
        const int arow = ll & 15, akg = ll >> 4;
        #pragma unroll
        for (int s = 0; s < 2; ++s) {
            const float* qp = &Qs[arow][s*32 + akg*8];
            float4 q0 = *(const float4*)qp;
            float4 q1 = *(const float4*)(qp + 4);
            float qv[8] = {q0.x,q0.y,q0.z,q0.w,q1.x,q1.y,q1.z,q1.w};
            #pragma unroll
            for (int j = 0; j < 8; ++j) {
                ushort hh, lo2;
                limb2(qv[j], hh, lo2);
                aH[s][j] = (short)hh; aL[s][j] = (short)lo2;
            }
        }
    }

    unsigned ku[64];                     // this lane's 64 owned quantized scores

    for (int c = 0; c < 8; ++c) {
        // each wave: 2 m-tiles of 16 keys, 3 MFMA per (tile,s)
        #pragma unroll
        for (int tile = 0; tile < 2; ++tile) {
            const int m0 = w*32 + tile*16;
            const int brow = m0 + (ll & 15);
            f32x4_t a_ = {0.f, 0.f, 0.f, 0.f};
            #pragma unroll
            for (int s = 0; s < 2; ++s) {
                int q2 = (s*4 + (ll >> 4)) ^ (brow & 7);
                int off = brow*64 + q2*8;
                bf16x8_t bH = *(const bf16x8_t*)&Klds0[off];
                bf16x8_t bL = *(const bf16x8_t*)&Klds1[off];
                a_ = __builtin_amdgcn_mfma_f32_16x16x32_bf16(aH[s], bH, a_, 0, 0, 0);
                a_ = __builtin_amdgcn_mfma_f32_16x16x32_bf16(aH[s], bL, a_, 0, 0, 0);
                a_ = __builtin_amdgcn_mfma_f32_16x16x32_bf16(aL[s], bH, a_, 0, 0, 0);
            }
            const int qr = (ll >> 4) * 4;
            const int mcol = m0 + (ll & 15);
            sc[qr+0][mcol] = a_[0];
            sc[qr+1][mcol] = a_[1];
            sc[qr+2][mcol] = a_[2];
            sc[qr+3][mcol] = a_[3];
        }
        __syncthreads();

        // owner lanes pull + quantize to 21-bit fixed point (monotone)
        if ((l >> 1) == c) {
            const int half = l & 1;
            #pragma unroll
            for (int jq = 0; jq < 16; ++jq) {
                float4 v4 = *(const float4*)&sc[r][half*64 + jq*4];
                float vv[4] = {v4.x, v4.y, v4.z, v4.w};
                #pragma unroll
                for (int e = 0; e < 4; ++e) {
                    float vc = fminf(fmaxf(vv[e], -31.9f), 31.9f);
                    ku[jq*4 + e] = (unsigned)(int)fmaf(vc, 32768.f, 1048576.f);
                }
            }
        }
        // stage next chunk (Klds reads for this chunk are all before the barrier above)
        if (c < 7) {
            const size_t cb = (size_t)(c + 1) * 128 * 64;
            const float4* gh = (const float4*)(KHb + cb);
            const float4* gl = (const float4*)(KLb + cb);
            float4* lh = (float4*)Klds0;
            float4* lo = (float4*)Klds1;
            #pragma unroll
            for (int i = 0; i < 4; ++i) {
                lh[t + i*256] = gh[t + i*256];
                lo[t + i*256] = gl[t + i*256];
            }
        }
        __syncthreads();
    }

    // ---- row max (quantized domain) ----
    unsigned kumax = 0u;
    #pragma unroll
    for (int j = 0; j < 64; ++j) kumax = (ku[j] > kumax) ? ku[j] : kumax;
    #pragma unroll
    for (int off = 8; off; off >>= 1) {
        unsigned o = __shfl_xor(kumax, off, 16);
        kumax = (o > kumax) ? o : kumax;
    }

    // ---- exact 64th-largest via 3-stage radix select (bits [20:13],[12:5],[4:0]) ----
    int tgt = 64;
    radix_stage(hist, r, l, ku, 0u, 0u, 13, 256, tgt, piv);
    unsigned pref = (unsigned)piv[r].x << 13; tgt = piv[r].y;
    radix_stage(hist, r, l, ku, pref, 0x1FE000u, 5, 256, tgt, piv);
    pref |= (unsigned)piv[r].x << 5; tgt = piv[r].y;
    radix_stage(hist, r, l, ku, pref, 0x1FFFE0u, 0, 32, tgt, piv);
    const unsigned thr = pref | (unsigned)piv[r].x;

    // ---- boundary hedge: band = thr +- 2 quanta (~+-6.1e-5 raw score) ----
    const unsigned bhi = thr + 2u;
    const unsigned blo = (thr > 2u) ? thr - 2u : 0u;
    int cdef = 0, cbnd = 0;
    #pragma unroll
    for (int j = 0; j < 64; ++j) {
        unsigned k = ku[j];
        cdef += (k > bhi) ? 1 : 0;
        cbnd += (k >= blo && k <= bhi) ? 1 : 0;
    }
    int gi = cdef, ei = cbnd;
    #pragma unroll
    for (int off = 1; off < 16; off <<= 1) {
        int g = __shfl_up(gi, off, 16);
        int e = __shfl_up(ei, off, 16);
        if (l >= off) { gi += g; ei += e; }
    }
    const int def_excl = gi - cdef, bnd_excl = ei - cbnd;
    const int D_tot = __shfl(gi, 15, 16);
    const int m_tot = __shfl(ei, 15, 16);
    const int j_need = 64 - D_tot;
    const float frac = (float)j_need / (float)m_tot;

    float lsum = 0.f;
    int dpos = def_excl, bpos = bnd_excl;
    #pragma unroll
    for (int j = 0; j < 64; ++j) {
        unsigned k = ku[j];
        int slot = -1; float wgt = 0.f;
        if (k > bhi) {
            slot = dpos++;
            wgt = __expf((float)(int)(k - kumax) * 3.814697265625e-6f);  // 0.125/32768
        } else if (k >= blo) {
            slot = D_tot + (bpos++);
            wgt = __expf((float)(int)(k - kumax) * 3.814697265625e-6f) * frac;
        }
        if (slot >= 0 && slot < MAXSEL) {
            selm[r][slot] = (ushort)(l*64 + j);
            selw[r][slot] = wgt;
            lsum += wgt;
        }
    }
    #pragma unroll
    for (int off = 8; off; off >>= 1) lsum += __shfl_xor(lsum, off, 16);
    if (l == 0) {
        rowsum[r] = lsum;
        int ct = D_tot + m_tot;
        rowcnt[r] = (ct > MAXSEL) ? MAXSEL : ct;
    }
    __syncthreads();

    // ---- PV ----
    {
        const int d = t & 63, qg = t >> 6;
        const int bb = bh >> 4, hh = bh & 15;
        #pragma unroll
        for (int i = 0; i < 4; ++i) {
            int q = qg*4 + i;
            int cend = rowcnt[q];
            float a = 0.f;
            for (int j = 0; j < cend; ++j) {
                a += selw[q][j] * Vbase[(size_t)selm[q][j] * 64 + d];
            }
            outp[((size_t)bb*1024 + (n0 + q)) * 1024 + hh*64 + d] = a / rowsum[q];
        }
    }
}

extern "C" void kernel_launch(void* const* d_in, const int* in_sizes, int n_in,
                              void* d_out, int out_size, void* d_ws, size_t ws_size,
                              hipStream_t stream) {
    const float* x     = (const float*)d_in[0];
    const float* Wq    = (const float*)d_in[1];
    const float* bq    = (const float*)d_in[2];
    const float* Wk    = (const float*)d_in[3];
    const float* bk    = (const float*)d_in[4];
    const float* Wv    = (const float*)d_in[5];
    const float* bv    = (const float*)d_in[6];
    const float* Wo    = (const float*)d_in[7];
    const float* bo    = (const float*)d_in[8];
    const float* statk = (const float*)d_in[9];
    float* out = (float*)d_out;
    float* ws  = (float*)d_ws;

    const size_t NF = (size_t)1 << 22;   // 4M elements per [64bh][1024][64] array

    float*  Qw = ws;                     // f32
    float*  Vw = ws + NF;                // f32
    float*  op = ws + 2 * NF;            // f32
    ushort* KH = (ushort*)(ws + 3 * NF); // bf16 limb hi (pre-swizzled)
    ushort* KL = KH + NF;                // bf16 limb lo

    dim3 g1(24, 32);
    gemm_qkv_kernel<<<g1, 256, 0, stream>>>(x, Wq, bq, Wk, bk, Wv, bv, statk,
                                            Qw, Vw, KH, KL);
    attn_mfma_kernel<<<4096, 256, 0, stream>>>(Qw, KH, KL, Vw, op);
    dim3 g2(8, 32);
    gemm_out_kernel<<<g2, 256, 0, stream>>>(op, Wo, bo, out);
}

// Round 6
// 472.740 us; speedup vs baseline: 2.1214x; 1.4562x over previous
//
#include <hip/hip_runtime.h>

#define NSTAT 32
#define MAXSEL 76

typedef __attribute__((ext_vector_type(8))) short bf16x8_t;
typedef __attribute__((ext_vector_type(4))) float f32x4_t;

#define GLOAD_LDS16(g, l) \
    __builtin_amdgcn_global_load_lds((const __attribute__((address_space(1))) void*)(g), \
                                     (__attribute__((address_space(3))) void*)(l), 16, 0, 0)

// round-to-nearest-even bf16
__device__ __forceinline__ ushort rtn_bf16(float a) {
    unsigned u = __float_as_uint(a);
    return (ushort)((u + 0x7FFFu + ((u >> 16) & 1u)) >> 16);
}
// 2-limb RTN decomposition: a ~= hi + lo, residual <= 2^-18|a|
__device__ __forceinline__ void limb2(float a, ushort& h, ushort& l) {
    ushort hh = rtn_bf16(a);
    float fh = __uint_as_float(((unsigned)hh) << 16);
    float r1 = a - fh;
    l = rtn_bf16(r1);
    h = hh;
}
// exact 3-limb truncation decomposition: hi+mid+lo == a (fp32 24-bit mantissa = 8+8+8)
__device__ __forceinline__ void limb3(float a, ushort& h, ushort& m, ushort& l) {
    unsigned u = __float_as_uint(a);
    unsigned uh = u & 0xFFFF0000u;
    float fh = __uint_as_float(uh);
    float r1 = a - fh;
    unsigned um = __float_as_uint(r1) & 0xFFFF0000u;
    float fm = __uint_as_float(um);
    float r2 = r1 - fm;
    h = (ushort)(uh >> 16);
    m = (ushort)(um >> 16);
    l = (ushort)(__float_as_uint(r2) >> 16);
}

// ---------------- weight limb decomposition (pre-swizzled tile layout) ----------------
// layout: flat = row*1024 + kt*32 + (q ^ (row&3))*8 + e   (q = logical quad of k within kt-tile)
__global__ __launch_bounds__(256)
void decomp_w_kernel(const float* __restrict__ Wq, const float* __restrict__ Wk,
                     const float* __restrict__ Wv, const float* __restrict__ Wo,
                     ushort* __restrict__ WL, ushort* __restrict__ WoL)
{
    const int m = blockIdx.y;
    const float* src = (m == 0) ? Wq : (m == 1) ? Wk : (m == 2) ? Wv : Wo;
    const int idx = blockIdx.x * 256 + threadIdx.x;     // 0..131071
    const int e8 = idx * 8;
    const int row = e8 >> 10, k0 = e8 & 1023;
    const int kt = k0 >> 5, q = (k0 >> 3) & 3;
    const size_t doff = ((size_t)row << 10) + (size_t)(kt * 32) + (size_t)((q ^ (row & 3)) * 8);

    float4 v0 = *(const float4*)(src + e8);
    float4 v1 = *(const float4*)(src + e8 + 4);
    float f[8] = {v0.x, v0.y, v0.z, v0.w, v1.x, v1.y, v1.z, v1.w};

    const unsigned Mi = 1u << 20;
    if (m == 2) {
        ushort h[8], l[8];
        #pragma unroll
        for (int e = 0; e < 8; ++e) limb2(f[e], h[e], l[e]);
        ushort* H = WL + (size_t)6 * Mi;
        ushort* L = WL + (size_t)7 * Mi;
        *(ushort4*)(H + doff) = make_ushort4(h[0],h[1],h[2],h[3]);
        *(ushort4*)(H + doff + 4) = make_ushort4(h[4],h[5],h[6],h[7]);
        *(ushort4*)(L + doff) = make_ushort4(l[0],l[1],l[2],l[3]);
        *(ushort4*)(L + doff + 4) = make_ushort4(l[4],l[5],l[6],l[7]);
    } else {
        ushort h[8], mm[8], l[8];
        #pragma unroll
        for (int e = 0; e < 8; ++e) limb3(f[e], h[e], mm[e], l[e]);
        ushort* H = (m == 3) ? WoL : WL + (size_t)(m * 3) * Mi;
        ushort* M = H + Mi;
        ushort* L = M + Mi;
        *(ushort4*)(H + doff) = make_ushort4(h[0],h[1],h[2],h[3]);
        *(ushort4*)(H + doff + 4) = make_ushort4(h[4],h[5],h[6],h[7]);
        *(ushort4*)(M + doff) = make_ushort4(mm[0],mm[1],mm[2],mm[3]);
        *(ushort4*)(M + doff + 4) = make_ushort4(mm[4],mm[5],mm[6],mm[7]);
        *(ushort4*)(L + doff) = make_ushort4(l[0],l[1],l[2],l[3]);
        *(ushort4*)(L + doff + 4) = make_ushort4(l[4],l[5],l[6],l[7]);
    }
}

// ---------------- limb-MFMA GEMM: C[128x128] = A[128,1024] @ W[128,1024]^T ----------------
// A fp32 decomposed on the fly (3-limb); B pre-decomposed pre-swizzled bf16 limbs via global_load_lds.
// mode: 0=Q (f32 out), 1=K (limb2 swizzled out), 2=V (f32 out, 3-product), 3=OUT (f32 row-major + bo)
__global__ __launch_bounds__(256, 2)
void limb_gemm_kernel(const float* __restrict__ A,
                      const ushort* __restrict__ WL, const ushort* __restrict__ WoL,
                      const float* __restrict__ bq, const float* __restrict__ bk,
                      const float* __restrict__ bv, const float* __restrict__ bo,
                      const float* __restrict__ statk,
                      float* __restrict__ Qw, float* __restrict__ Vw,
                      ushort* __restrict__ KHo, ushort* __restrict__ KLo,
                      float* __restrict__ Cout, int is_out)
{
    __shared__ __align__(16) ushort Al[3][128][32];
    __shared__ __align__(16) ushort Bl[2][3][128][32];

    const int t = threadIdx.x;
    const int bx = blockIdx.x, by = blockIdx.y;
    const int mode = is_out ? 3 : (int)blockIdx.z;
    const int np6 = (mode != 2);
    const int nBlimb = np6 ? 3 : 2;
    const int wc0 = bx * 128;
    const int arow0 = by * 128;

    const unsigned Mi = 1u << 20;
    const ushort* Bp[3];
    const float* bias;
    if (mode == 0)      { Bp[0] = WL;          Bp[1] = WL + Mi;     Bp[2] = WL + 2*Mi; bias = bq; }
    else if (mode == 1) { Bp[0] = WL + 3*Mi;   Bp[1] = WL + 4*Mi;   Bp[2] = WL + 5*Mi; bias = bk; }
    else if (mode == 2) { Bp[0] = WL + 6*Mi;   Bp[1] = WL + 7*Mi;   Bp[2] = nullptr;   bias = bv; }
    else                { Bp[0] = WoL;         Bp[1] = WoL + Mi;    Bp[2] = WoL + 2*Mi; bias = bo; }

    const int ll = t & 63, w = t >> 6;

    f32x4_t acc[4][4];
    #pragma unroll
    for (int i = 0; i < 4; ++i)
        #pragma unroll
        for (int j = 0; j < 4; ++j) acc[i][j] = (f32x4_t){0.f, 0.f, 0.f, 0.f};

    // ---- staging helpers ----
    // B: global_load_lds, pre-swizzled source, linear LDS dest. 8KB/limb = 8 wave-calls of 1KB.
    auto stageB = [&](int kt, int bb) {
        #pragma unroll
        for (int limb = 0; limb < 3; ++limb) {
            if (limb >= nBlimb) break;
            const ushort* src = Bp[limb];
            #pragma unroll
            for (int call = 0; call < 2; ++call) {
                int chunk = (w * 2 + call) * 64 + ll;          // 0..511
                int eoff = chunk * 8;
                int row = eoff >> 5, qp = (eoff >> 3) & 3;
                const ushort* g = src + ((size_t)(wc0 + row) << 10) + kt * 32 + qp * 8;
                char* l = ((char*)&Bl[bb][limb][0][0]) + (w * 2 + call) * 1024;
                GLOAD_LDS16(g, l);
            }
        }
    };
    // A: fp32 global -> regs
    const int srow = t >> 1, skh = (t & 1) * 16;
    auto loadA = [&](int kt, float4* a4) {
        const float* p = A + (((size_t)(arow0 + srow)) << 10) + kt * 32 + skh;
        a4[0] = *(const float4*)(p + 0);
        a4[1] = *(const float4*)(p + 4);
        a4[2] = *(const float4*)(p + 8);
        a4[3] = *(const float4*)(p + 12);
    };
    // regs -> limb3 -> swizzled ds_write
    auto writeA = [&](const float4* a4) {
        float f[16];
        #pragma unroll
        for (int i = 0; i < 4; ++i) {
            f[i*4+0] = a4[i].x; f[i*4+1] = a4[i].y; f[i*4+2] = a4[i].z; f[i*4+3] = a4[i].w;
        }
        ushort h[16], m[16], lo[16];
        #pragma unroll
        for (int e = 0; e < 16; ++e) limb3(f[e], h[e], m[e], lo[e]);
        const int sw = srow & 3;
        #pragma unroll
        for (int qq = 0; qq < 2; ++qq) {
            int q = (skh >> 3) + qq;
            int qo = (q ^ sw) * 8;
            bf16x8_t vH, vM, vL;
            #pragma unroll
            for (int e = 0; e < 8; ++e) {
                vH[e] = (short)h[qq*8+e]; vM[e] = (short)m[qq*8+e]; vL[e] = (short)lo[qq*8+e];
            }
            *(bf16x8_t*)&Al[0][srow][qo] = vH;
            *(bf16x8_t*)&Al[1][srow][qo] = vM;
            *(bf16x8_t*)&Al[2][srow][qo] = vL;
        }
    };

    const int wr = (w >> 1) * 64, wcv = (w & 1) * 64;
    const int fr = ll & 15, kg = ll >> 4;

    auto compute = [&](int bb) {
        bf16x8_t af[4][3];
        #pragma unroll
        for (int i = 0; i < 4; ++i) {
            int row = wr + i * 16 + fr;
            int qo = (kg ^ (row & 3)) * 8;
            af[i][0] = *(const bf16x8_t*)&Al[0][row][qo];
            af[i][1] = *(const bf16x8_t*)&Al[1][row][qo];
            af[i][2] = *(const bf16x8_t*)&Al[2][row][qo];
        }
        #pragma unroll
        for (int j = 0; j < 4; ++j) {
            int row = wcv + j * 16 + fr;
            int qo = (kg ^ (row & 3)) * 8;
            bf16x8_t b0 = *(const bf16x8_t*)&Bl[bb][0][row][qo];
            bf16x8_t b1 = *(const bf16x8_t*)&Bl[bb][1][row][qo];
            if (np6) {
                bf16x8_t b2 = *(const bf16x8_t*)&Bl[bb][2][row][qo];
                #pragma unroll
                for (int i = 0; i < 4; ++i) {
                    acc[i][j] = __builtin_amdgcn_mfma_f32_16x16x32_bf16(af[i][0], b0, acc[i][j], 0, 0, 0);
                    acc[i][j] = __builtin_amdgcn_mfma_f32_16x16x32_bf16(af[i][0], b1, acc[i][j], 0, 0, 0);
                    acc[i][j] = __builtin_amdgcn_mfma_f32_16x16x32_bf16(af[i][1], b0, acc[i][j], 0, 0, 0);
                    acc[i][j] = __builtin_amdgcn_mfma_f32_16x16x32_bf16(af[i][1], b1, acc[i][j], 0, 0, 0);
                    acc[i][j] = __builtin_amdgcn_mfma_f32_16x16x32_bf16(af[i][0], b2, acc[i][j], 0, 0, 0);
                    acc[i][j] = __builtin_amdgcn_mfma_f32_16x16x32_bf16(af[i][2], b0, acc[i][j], 0, 0, 0);
                }
            } else {
                #pragma unroll
                for (int i = 0; i < 4; ++i) {
                    acc[i][j] = __builtin_amdgcn_mfma_f32_16x16x32_bf16(af[i][0], b0, acc[i][j], 0, 0, 0);
                    acc[i][j] = __builtin_amdgcn_mfma_f32_16x16x32_bf16(af[i][1], b0, acc[i][j], 0, 0, 0);
                    acc[i][j] = __builtin_amdgcn_mfma_f32_16x16x32_bf16(af[i][0], b1, acc[i][j], 0, 0, 0);
                }
            }
        }
    };

    // ---- prologue: stage tile 0 ----
    float4 a4[4];
    loadA(0, a4);
    writeA(a4);
    stageB(0, 0);
    __syncthreads();

    // ---- main loop ----
    float4 a4n[4];
    for (int kt = 0; kt < 32; ++kt) {
        int bb = kt & 1;
        if (kt < 31) {
            stageB(kt + 1, bb ^ 1);
            loadA(kt + 1, a4n);
        }
        compute(bb);
        __syncthreads();
        if (kt < 31) writeA(a4n);
        __syncthreads();
    }

    // ---- epilogue ----
    #pragma unroll
    for (int i = 0; i < 4; ++i) {
        #pragma unroll
        for (int j = 0; j < 4; ++j) {
            int c = wc0 + wcv + j * 16 + (ll & 15);
            float bv_ = bias[c];
            #pragma unroll
            for (int q = 0; q < 4; ++q) {
                int gr = arow0 + wr + i * 16 + (kg) * 4 + q;
                float v = acc[i][j][q] + bv_;
                if (mode == 3) {
                    Cout[(size_t)gr * 1024 + c] = v;
                } else {
                    int b = gr >> 10, n = gr & 1023;
                    int h = c >> 6, d = c & 63;
                    size_t bhn = ((size_t)(b * 16 + h)) * 1024 + n;
                    if (mode == 1) {
                        if (n < NSTAT) v = statk[n * 1024 + c];
                        ushort kh, klo;
                        limb2(v, kh, klo);
                        size_t off = bhn * 64 + (size_t)(((d >> 3) ^ (n & 7)) * 8) + (d & 7);
                        KHo[off] = kh;
                        KLo[off] = klo;
                    } else {
                        float* Out = (mode == 0) ? Qw : Vw;
                        Out[bhn * 64 + d] = v;
                    }
                }
            }
        }
    }
}

// ---------------- radix-select stage (per 16-lane row group) ----------------
__device__ __forceinline__ void radix_stage(int* __restrict__ hist, int r, int l,
                                            const unsigned* __restrict__ ku,
                                            unsigned pref, unsigned prefmask,
                                            int shift, int nbins, int tgt,
                                            int2* __restrict__ piv)
{
    const int per = nbins >> 4;
    #pragma unroll
    for (int b = 0; b < 16; ++b)
        if (b < per) hist[r*256 + l*per + b] = 0;
    __syncthreads();
    #pragma unroll
    for (int j = 0; j < 64; ++j) {
        unsigned k = ku[j];
        if ((k & prefmask) == pref)
            atomicAdd(&hist[r*256 + (int)((k >> shift) & (unsigned)(nbins - 1))], 1);
    }
    __syncthreads();
    int seg = 0;
    for (int b = 0; b < per; ++b) seg += hist[r*256 + l*per + b];
    int suf = seg;
    #pragma unroll
    for (int off = 1; off < 16; off <<= 1) {
        int v = __shfl_down(suf, off, 16);
        suf += (l + off < 16) ? v : 0;
    }
    const int above = suf - seg;
    if (above < tgt && above + seg >= tgt) {
        int c = above;
        for (int b = per - 1; b >= 0; --b) {
            int h = hist[r*256 + l*per + b];
            if (c + h >= tgt) { piv[r] = make_int2(l*per + b, tgt - c); break; }
            c += h;
        }
    }
    __syncthreads();
}

// ---------------- MFMA attn: 2-limb bf16 scores + radix top-64 + hedge + PV ----------------
__global__ __launch_bounds__(256)
void attn_mfma_kernel(const float* __restrict__ Qw,
                      const ushort* __restrict__ KH, const ushort* __restrict__ KL,
                      const float* __restrict__ Vw, float* __restrict__ outp)
{
    __shared__ __align__(16) float Qs[16][68];
    __shared__ __align__(16) unsigned char kpool[2 * 128 * 64 * 2];
    __shared__ __align__(16) float sc[16][132];
    __shared__ ushort selm[16][MAXSEL];
    __shared__ __align__(16) float selw[16][MAXSEL];
    __shared__ int2 piv[16];
    __shared__ float rowsum[16];
    __shared__ int   rowcnt[16];

    ushort* Klds0 = (ushort*)kpool;
    ushort* Klds1 = Klds0 + 128 * 64;
    int* hist = (int*)kpool;

    const int t = threadIdx.x;
    const int bid0 = blockIdx.x;
    const int bid = (bid0 & 7) * 512 + (bid0 >> 3);
    const int qt = bid & 63;
    const int bh = bid >> 6;
    const int n0 = qt * 16;
    const float* Qbase = Qw + ((size_t)bh * 1024 + n0) * 64;
    const float* Vbase = Vw + (size_t)bh * 1024 * 64;
    const ushort* KHb = KH + (size_t)bh * 1024 * 64;
    const ushort* KLb = KL + (size_t)bh * 1024 * 64;

    const int ll = t & 63;
    const int w  = t >> 6;
    const int r  = t >> 4, l = t & 15;

    {
        int q = t >> 4, dq = (t & 15) * 4;
        *(float4*)&Qs[q][dq] = *(const float4*)(Qbase + q * 64 + dq);
    }
    {
        const float4* gh = (const float4*)KHb;
        const float4* gl = (const float4*)KLb;
        float4* lh = (float4*)Klds0;
        float4* lo = (float4*)Klds1;
        #pragma unroll
        for (int i = 0; i < 4; ++i) {
            lh[t + i*256] = gh[t + i*256];
            lo[t + i*256] = gl[t + i*256];
        }
    }
    __syncthreads();

    bf16x8_t aH[2], aL[2];
    {
        const int arow = ll & 15, akg = ll >> 4;
        #pragma unroll
        for (int s = 0; s < 2; ++s) {
            const float* qp = &Qs[arow][s*32 + akg*8];
            float4 q0 = *(const float4*)qp;
            float4 q1 = *(const float4*)(qp + 4);
            float qv[8] = {q0.x,q0.y,q0.z,q0.w,q1.x,q1.y,q1.z,q1.w};
            #pragma unroll
            for (int j = 0; j < 8; ++j) {
                ushort hh, lo2;
                limb2(qv[j], hh, lo2);
                aH[s][j] = (short)hh; aL[s][j] = (short)lo2;
            }
        }
    }

    unsigned ku[64];

    for (int c = 0; c < 8; ++c) {
        #pragma unroll
        for (int tile = 0; tile < 2; ++tile) {
            const int m0 = w*32 + tile*16;
            const int brow = m0 + (ll & 15);
            f32x4_t a_ = {0.f, 0.f, 0.f, 0.f};
            #pragma unroll
            for (int s = 0; s < 2; ++s) {
                int q2 = (s*4 + (ll >> 4)) ^ (brow & 7);
                int off = brow*64 + q2*8;
                bf16x8_t bH = *(const bf16x8_t*)&Klds0[off];
                bf16x8_t bL = *(const bf16x8_t*)&Klds1[off];
                a_ = __builtin_amdgcn_mfma_f32_16x16x32_bf16(aH[s], bH, a_, 0, 0, 0);
                a_ = __builtin_amdgcn_mfma_f32_16x16x32_bf16(aH[s], bL, a_, 0, 0, 0);
                a_ = __builtin_amdgcn_mfma_f32_16x16x32_bf16(aL[s], bH, a_, 0, 0, 0);
            }
            const int qr = (ll >> 4) * 4;
            const int mcol = m0 + (ll & 15);
            sc[qr+0][mcol] = a_[0];
            sc[qr+1][mcol] = a_[1];
            sc[qr+2][mcol] = a_[2];
            sc[qr+3][mcol] = a_[3];
        }
        __syncthreads();

        if ((l >> 1) == c) {
            const int half = l & 1;
            #pragma unroll
            for (int jq = 0; jq < 16; ++jq) {
                float4 v4 = *(const float4*)&sc[r][half*64 + jq*4];
                float vv[4] = {v4.x, v4.y, v4.z, v4.w};
                #pragma unroll
                for (int e = 0; e < 4; ++e) {
                    float vc = fminf(fmaxf(vv[e], -31.9f), 31.9f);
                    ku[jq*4 + e] = (unsigned)(int)fmaf(vc, 32768.f, 1048576.f);
                }
            }
        }
        if (c < 7) {
            const size_t cb = (size_t)(c + 1) * 128 * 64;
            const float4* gh = (const float4*)(KHb + cb);
            const float4* gl = (const float4*)(KLb + cb);
            float4* lh = (float4*)Klds0;
            float4* lo = (float4*)Klds1;
            #pragma unroll
            for (int i = 0; i < 4; ++i) {
                lh[t + i*256] = gh[t + i*256];
                lo[t + i*256] = gl[t + i*256];
            }
        }
        __syncthreads();
    }

    unsigned kumax = 0u;
    #pragma unroll
    for (int j = 0; j < 64; ++j) kumax = (ku[j] > kumax) ? ku[j] : kumax;
    #pragma unroll
    for (int off = 8; off; off >>= 1) {
        unsigned o = __shfl_xor(kumax, off, 16);
        kumax = (o > kumax) ? o : kumax;
    }

    int tgt = 64;
    radix_stage(hist, r, l, ku, 0u, 0u, 13, 256, tgt, piv);
    unsigned pref = (unsigned)piv[r].x << 13; tgt = piv[r].y;
    radix_stage(hist, r, l, ku, pref, 0x1FE000u, 5, 256, tgt, piv);
    pref |= (unsigned)piv[r].x << 5; tgt = piv[r].y;
    radix_stage(hist, r, l, ku, pref, 0x1FFFE0u, 0, 32, tgt, piv);
    const unsigned thr = pref | (unsigned)piv[r].x;

    const unsigned bhi = thr + 2u;
    const unsigned blo = (thr > 2u) ? thr - 2u : 0u;
    int cdef = 0, cbnd = 0;
    #pragma unroll
    for (int j = 0; j < 64; ++j) {
        unsigned k = ku[j];
        cdef += (k > bhi) ? 1 : 0;
        cbnd += (k >= blo && k <= bhi) ? 1 : 0;
    }
    int gi = cdef, ei = cbnd;
    #pragma unroll
    for (int off = 1; off < 16; off <<= 1) {
        int g = __shfl_up(gi, off, 16);
        int e = __shfl_up(ei, off, 16);
        if (l >= off) { gi += g; ei += e; }
    }
    const int def_excl = gi - cdef, bnd_excl = ei - cbnd;
    const int D_tot = __shfl(gi, 15, 16);
    const int m_tot = __shfl(ei, 15, 16);
    const int j_need = 64 - D_tot;
    const float frac = (float)j_need / (float)m_tot;

    float lsum = 0.f;
    int dpos = def_excl, bpos = bnd_excl;
    #pragma unroll
    for (int j = 0; j < 64; ++j) {
        unsigned k = ku[j];
        int slot = -1; float wgt = 0.f;
        if (k > bhi) {
            slot = dpos++;
            wgt = __expf((float)(int)(k - kumax) * 3.814697265625e-6f);
        } else if (k >= blo) {
            slot = D_tot + (bpos++);
            wgt = __expf((float)(int)(k - kumax) * 3.814697265625e-6f) * frac;
        }
        if (slot >= 0 && slot < MAXSEL) {
            selm[r][slot] = (ushort)(l*64 + j);
            selw[r][slot] = wgt;
            lsum += wgt;
        }
    }
    #pragma unroll
    for (int off = 8; off; off >>= 1) lsum += __shfl_xor(lsum, off, 16);
    if (l == 0) {
        rowsum[r] = lsum;
        int ct = D_tot + m_tot;
        rowcnt[r] = (ct > MAXSEL) ? MAXSEL : ct;
    }
    __syncthreads();

    {
        const int d = t & 63, qg = t >> 6;
        const int bb = bh >> 4, hh = bh & 15;
        #pragma unroll
        for (int i = 0; i < 4; ++i) {
            int q = qg*4 + i;
            int cend = rowcnt[q];
            float a = 0.f;
            for (int j = 0; j < cend; ++j) {
                a += selw[q][j] * Vbase[(size_t)selm[q][j] * 64 + d];
            }
            outp[((size_t)bb*1024 + (n0 + q)) * 1024 + hh*64 + d] = a / rowsum[q];
        }
    }
}

extern "C" void kernel_launch(void* const* d_in, const int* in_sizes, int n_in,
                              void* d_out, int out_size, void* d_ws, size_t ws_size,
                              hipStream_t stream) {
    const float* x     = (const float*)d_in[0];
    const float* Wq    = (const float*)d_in[1];
    const float* bq    = (const float*)d_in[2];
    const float* Wk    = (const float*)d_in[3];
    const float* bk    = (const float*)d_in[4];
    const float* Wv    = (const float*)d_in[5];
    const float* bv    = (const float*)d_in[6];
    const float* Wo    = (const float*)d_in[7];
    const float* bo    = (const float*)d_in[8];
    const float* statk = (const float*)d_in[9];
    float* out = (float*)d_out;
    float* ws  = (float*)d_ws;

    const size_t NF = (size_t)1 << 22;   // 4Mi elems (16 MiB f32)

    // layout (ws >= 72 MiB proven):
    // [0,16)MiB  Qw f32
    // [16,32)    Vw f32
    // [32,48)    W-limbs (QKV) during GEMM phase; op f32 (written by attn) afterwards — alias OK
    // [48,64)    KH, KL bf16 limbs
    // [64,70)    Wo limbs
    float*  Qw  = ws;
    float*  Vw  = ws + NF;
    ushort* WL  = (ushort*)(ws + 2 * NF);
    float*  op  = ws + 2 * NF;
    ushort* KH  = (ushort*)(ws + 3 * NF);
    ushort* KL  = KH + NF;
    ushort* WoL = (ushort*)(ws + 4 * NF);

    dim3 gd(512, 4);
    decomp_w_kernel<<<gd, 256, 0, stream>>>(Wq, Wk, Wv, Wo, WL, WoL);

    dim3 g1(8, 32, 3);
    limb_gemm_kernel<<<g1, 256, 0, stream>>>(x, WL, WoL, bq, bk, bv, bo, statk,
                                             Qw, Vw, KH, KL, nullptr, 0);

    attn_mfma_kernel<<<4096, 256, 0, stream>>>(Qw, KH, KL, Vw, op);

    dim3 g2(8, 32, 1);
    limb_gemm_kernel<<<g2, 256, 0, stream>>>(op, WL, WoL, bq, bk, bv, bo, statk,
                                             Qw, Vw, KH, KL, out, 1);
}

// Round 7
// 390.800 us; speedup vs baseline: 2.5662x; 1.2097x over previous
//
#include <hip/hip_runtime.h>

#define NSTAT 32
#define MAXSEL 76

typedef __attribute__((ext_vector_type(8))) short bf16x8_t;
typedef __attribute__((ext_vector_type(4))) float f32x4_t;

#define GLOAD_LDS16(g, l) \
    __builtin_amdgcn_global_load_lds((const __attribute__((address_space(1))) void*)(g), \
                                     (__attribute__((address_space(3))) void*)(l), 16, 0, 0)

// round-to-nearest-even bf16
__device__ __forceinline__ ushort rtn_bf16(float a) {
    unsigned u = __float_as_uint(a);
    return (ushort)((u + 0x7FFFu + ((u >> 16) & 1u)) >> 16);
}
// 2-limb RTN decomposition
__device__ __forceinline__ void limb2(float a, ushort& h, ushort& l) {
    ushort hh = rtn_bf16(a);
    float fh = __uint_as_float(((unsigned)hh) << 16);
    float r1 = a - fh;
    l = rtn_bf16(r1);
    h = hh;
}
// exact 3-limb truncation decomposition
__device__ __forceinline__ void limb3(float a, ushort& h, ushort& m, ushort& l) {
    unsigned u = __float_as_uint(a);
    unsigned uh = u & 0xFFFF0000u;
    float fh = __uint_as_float(uh);
    float r1 = a - fh;
    unsigned um = __float_as_uint(r1) & 0xFFFF0000u;
    float fm = __uint_as_float(um);
    float r2 = r1 - fm;
    h = (ushort)(uh >> 16);
    m = (ushort)(um >> 16);
    l = (ushort)(__float_as_uint(r2) >> 16);
}

// ---------------- weight limb decomposition (pre-swizzled tile layout) ----------------
__global__ __launch_bounds__(256)
void decomp_w_kernel(const float* __restrict__ Wq, const float* __restrict__ Wk,
                     const float* __restrict__ Wv, const float* __restrict__ Wo,
                     ushort* __restrict__ WL, ushort* __restrict__ WoL)
{
    const int m = blockIdx.y;
    const float* src = (m == 0) ? Wq : (m == 1) ? Wk : (m == 2) ? Wv : Wo;
    const int idx = blockIdx.x * 256 + threadIdx.x;
    const int e8 = idx * 8;
    const int row = e8 >> 10, k0 = e8 & 1023;
    const int kt = k0 >> 5, q = (k0 >> 3) & 3;
    const size_t doff = ((size_t)row << 10) + (size_t)(kt * 32) + (size_t)((q ^ (row & 3)) * 8);

    float4 v0 = *(const float4*)(src + e8);
    float4 v1 = *(const float4*)(src + e8 + 4);
    float f[8] = {v0.x, v0.y, v0.z, v0.w, v1.x, v1.y, v1.z, v1.w};

    const unsigned Mi = 1u << 20;
    if (m == 2) {
        ushort h[8], l[8];
        #pragma unroll
        for (int e = 0; e < 8; ++e) limb2(f[e], h[e], l[e]);
        ushort* H = WL + (size_t)6 * Mi;
        ushort* L = WL + (size_t)7 * Mi;
        *(ushort4*)(H + doff) = make_ushort4(h[0],h[1],h[2],h[3]);
        *(ushort4*)(H + doff + 4) = make_ushort4(h[4],h[5],h[6],h[7]);
        *(ushort4*)(L + doff) = make_ushort4(l[0],l[1],l[2],l[3]);
        *(ushort4*)(L + doff + 4) = make_ushort4(l[4],l[5],l[6],l[7]);
    } else {
        ushort h[8], mm[8], l[8];
        #pragma unroll
        for (int e = 0; e < 8; ++e) limb3(f[e], h[e], mm[e], l[e]);
        ushort* H = (m == 3) ? WoL : WL + (size_t)(m * 3) * Mi;
        ushort* M = H + Mi;
        ushort* L = M + Mi;
        *(ushort4*)(H + doff) = make_ushort4(h[0],h[1],h[2],h[3]);
        *(ushort4*)(H + doff + 4) = make_ushort4(h[4],h[5],h[6],h[7]);
        *(ushort4*)(M + doff) = make_ushort4(mm[0],mm[1],mm[2],mm[3]);
        *(ushort4*)(M + doff + 4) = make_ushort4(mm[4],mm[5],mm[6],mm[7]);
        *(ushort4*)(L + doff) = make_ushort4(l[0],l[1],l[2],l[3]);
        *(ushort4*)(L + doff + 4) = make_ushort4(l[4],l[5],l[6],l[7]);
    }
}

// ---------------- limb-MFMA GEMM (unchanged from R6, validated) ----------------
__global__ __launch_bounds__(256, 2)
void limb_gemm_kernel(const float* __restrict__ A,
                      const ushort* __restrict__ WL, const ushort* __restrict__ WoL,
                      const float* __restrict__ bq, const float* __restrict__ bk,
                      const float* __restrict__ bv, const float* __restrict__ bo,
                      const float* __restrict__ statk,
                      float* __restrict__ Qw, float* __restrict__ Vw,
                      ushort* __restrict__ KHo, ushort* __restrict__ KLo,
                      float* __restrict__ Cout, int is_out)
{
    __shared__ __align__(16) ushort Al[3][128][32];
    __shared__ __align__(16) ushort Bl[2][3][128][32];

    const int t = threadIdx.x;
    const int bx = blockIdx.x, by = blockIdx.y;
    const int mode = is_out ? 3 : (int)blockIdx.z;
    const int np6 = (mode != 2);
    const int nBlimb = np6 ? 3 : 2;
    const int wc0 = bx * 128;
    const int arow0 = by * 128;

    const unsigned Mi = 1u << 20;
    const ushort* Bp[3];
    const float* bias;
    if (mode == 0)      { Bp[0] = WL;          Bp[1] = WL + Mi;     Bp[2] = WL + 2*Mi; bias = bq; }
    else if (mode == 1) { Bp[0] = WL + 3*Mi;   Bp[1] = WL + 4*Mi;   Bp[2] = WL + 5*Mi; bias = bk; }
    else if (mode == 2) { Bp[0] = WL + 6*Mi;   Bp[1] = WL + 7*Mi;   Bp[2] = nullptr;   bias = bv; }
    else                { Bp[0] = WoL;         Bp[1] = WoL + Mi;    Bp[2] = WoL + 2*Mi; bias = bo; }

    const int ll = t & 63, w = t >> 6;

    f32x4_t acc[4][4];
    #pragma unroll
    for (int i = 0; i < 4; ++i)
        #pragma unroll
        for (int j = 0; j < 4; ++j) acc[i][j] = (f32x4_t){0.f, 0.f, 0.f, 0.f};

    auto stageB = [&](int kt, int bb) {
        #pragma unroll
        for (int limb = 0; limb < 3; ++limb) {
            if (limb >= nBlimb) break;
            const ushort* src = Bp[limb];
            #pragma unroll
            for (int call = 0; call < 2; ++call) {
                int chunk = (w * 2 + call) * 64 + ll;
                int eoff = chunk * 8;
                int row = eoff >> 5, qp = (eoff >> 3) & 3;
                const ushort* g = src + ((size_t)(wc0 + row) << 10) + kt * 32 + qp * 8;
                char* l = ((char*)&Bl[bb][limb][0][0]) + (w * 2 + call) * 1024;
                GLOAD_LDS16(g, l);
            }
        }
    };
    const int srow = t >> 1, skh = (t & 1) * 16;
    auto loadA = [&](int kt, float4* a4) {
        const float* p = A + (((size_t)(arow0 + srow)) << 10) + kt * 32 + skh;
        a4[0] = *(const float4*)(p + 0);
        a4[1] = *(const float4*)(p + 4);
        a4[2] = *(const float4*)(p + 8);
        a4[3] = *(const float4*)(p + 12);
    };
    auto writeA = [&](const float4* a4) {
        float f[16];
        #pragma unroll
        for (int i = 0; i < 4; ++i) {
            f[i*4+0] = a4[i].x; f[i*4+1] = a4[i].y; f[i*4+2] = a4[i].z; f[i*4+3] = a4[i].w;
        }
        ushort h[16], m[16], lo[16];
        #pragma unroll
        for (int e = 0; e < 16; ++e) limb3(f[e], h[e], m[e], lo[e]);
        const int sw = srow & 3;
        #pragma unroll
        for (int qq = 0; qq < 2; ++qq) {
            int q = (skh >> 3) + qq;
            int qo = (q ^ sw) * 8;
            bf16x8_t vH, vM, vL;
            #pragma unroll
            for (int e = 0; e < 8; ++e) {
                vH[e] = (short)h[qq*8+e]; vM[e] = (short)m[qq*8+e]; vL[e] = (short)lo[qq*8+e];
            }
            *(bf16x8_t*)&Al[0][srow][qo] = vH;
            *(bf16x8_t*)&Al[1][srow][qo] = vM;
            *(bf16x8_t*)&Al[2][srow][qo] = vL;
        }
    };

    const int wr = (w >> 1) * 64, wcv = (w & 1) * 64;
    const int fr = ll & 15, kg = ll >> 4;

    auto compute = [&](int bb) {
        bf16x8_t af[4][3];
        #pragma unroll
        for (int i = 0; i < 4; ++i) {
            int row = wr + i * 16 + fr;
            int qo = (kg ^ (row & 3)) * 8;
            af[i][0] = *(const bf16x8_t*)&Al[0][row][qo];
            af[i][1] = *(const bf16x8_t*)&Al[1][row][qo];
            af[i][2] = *(const bf16x8_t*)&Al[2][row][qo];
        }
        #pragma unroll
        for (int j = 0; j < 4; ++j) {
            int row = wcv + j * 16 + fr;
            int qo = (kg ^ (row & 3)) * 8;
            bf16x8_t b0 = *(const bf16x8_t*)&Bl[bb][0][row][qo];
            bf16x8_t b1 = *(const bf16x8_t*)&Bl[bb][1][row][qo];
            if (np6) {
                bf16x8_t b2 = *(const bf16x8_t*)&Bl[bb][2][row][qo];
                #pragma unroll
                for (int i = 0; i < 4; ++i) {
                    acc[i][j] = __builtin_amdgcn_mfma_f32_16x16x32_bf16(af[i][0], b0, acc[i][j], 0, 0, 0);
                    acc[i][j] = __builtin_amdgcn_mfma_f32_16x16x32_bf16(af[i][0], b1, acc[i][j], 0, 0, 0);
                    acc[i][j] = __builtin_amdgcn_mfma_f32_16x16x32_bf16(af[i][1], b0, acc[i][j], 0, 0, 0);
                    acc[i][j] = __builtin_amdgcn_mfma_f32_16x16x32_bf16(af[i][1], b1, acc[i][j], 0, 0, 0);
                    acc[i][j] = __builtin_amdgcn_mfma_f32_16x16x32_bf16(af[i][0], b2, acc[i][j], 0, 0, 0);
                    acc[i][j] = __builtin_amdgcn_mfma_f32_16x16x32_bf16(af[i][2], b0, acc[i][j], 0, 0, 0);
                }
            } else {
                #pragma unroll
                for (int i = 0; i < 4; ++i) {
                    acc[i][j] = __builtin_amdgcn_mfma_f32_16x16x32_bf16(af[i][0], b0, acc[i][j], 0, 0, 0);
                    acc[i][j] = __builtin_amdgcn_mfma_f32_16x16x32_bf16(af[i][1], b0, acc[i][j], 0, 0, 0);
                    acc[i][j] = __builtin_amdgcn_mfma_f32_16x16x32_bf16(af[i][0], b1, acc[i][j], 0, 0, 0);
                }
            }
        }
    };

    float4 a4[4];
    loadA(0, a4);
    writeA(a4);
    stageB(0, 0);
    __syncthreads();

    float4 a4n[4];
    for (int kt = 0; kt < 32; ++kt) {
        int bb = kt & 1;
        if (kt < 31) {
            stageB(kt + 1, bb ^ 1);
            loadA(kt + 1, a4n);
        }
        compute(bb);
        __syncthreads();
        if (kt < 31) writeA(a4n);
        __syncthreads();
    }

    #pragma unroll
    for (int i = 0; i < 4; ++i) {
        #pragma unroll
        for (int j = 0; j < 4; ++j) {
            int c = wc0 + wcv + j * 16 + (ll & 15);
            float bv_ = bias[c];
            #pragma unroll
            for (int q = 0; q < 4; ++q) {
                int gr = arow0 + wr + i * 16 + (kg) * 4 + q;
                float v = acc[i][j][q] + bv_;
                if (mode == 3) {
                    Cout[(size_t)gr * 1024 + c] = v;
                } else {
                    int b = gr >> 10, n = gr & 1023;
                    int h = c >> 6, d = c & 63;
                    size_t bhn = ((size_t)(b * 16 + h)) * 1024 + n;
                    if (mode == 1) {
                        if (n < NSTAT) v = statk[n * 1024 + c];
                        ushort kh, klo;
                        limb2(v, kh, klo);
                        size_t off = bhn * 64 + (size_t)(((d >> 3) ^ (n & 7)) * 8) + (d & 7);
                        KHo[off] = kh;
                        KLo[off] = klo;
                    } else {
                        float* Out = (mode == 0) ? Qw : Vw;
                        Out[bhn * 64 + d] = v;
                    }
                }
            }
        }
    }
}

// ---------------- radix-select stage, 7-bit bins, padded hist[bin*33 + r] ----------------
__device__ __forceinline__ void radix_stage7(int* __restrict__ hist, int r, int l,
                                             const unsigned* __restrict__ ku,
                                             unsigned pref, unsigned mask, int shift,
                                             int tgt, int2* __restrict__ piv)
{
    #pragma unroll
    for (int b = 0; b < 8; ++b) hist[(l*8 + b)*33 + r] = 0;
    __syncthreads();
    #pragma unroll
    for (int j = 0; j < 64; ++j) {
        unsigned k = ku[j];
        if ((k & mask) == pref)
            atomicAdd(&hist[(int)((k >> shift) & 127u)*33 + r], 1);
    }
    __syncthreads();
    int seg = 0;
    #pragma unroll
    for (int b = 0; b < 8; ++b) seg += hist[(l*8 + b)*33 + r];
    int suf = seg;
    #pragma unroll
    for (int off = 1; off < 16; off <<= 1) {
        int v = __shfl_down(suf, off, 16);
        suf += (l + off < 16) ? v : 0;
    }
    const int above = suf - seg;
    if (above < tgt && above + seg >= tgt) {
        int c = above;
        #pragma unroll
        for (int b = 7; b >= 0; --b) {
            int h = hist[(l*8 + b)*33 + r];
            if (c + h >= tgt) { piv[r] = make_int2(l*8 + b, tgt - c); break; }
            c += h;
        }
    }
    __syncthreads();
}

// ---------------- MFMA attn v2: 32q/block, 512 threads, strided ownership ----------------
// ownership: lane (r = t>>4, l = t&15) owns keys {c*128 + l*8 + e}, slot j = c*8+e.
__global__ __launch_bounds__(512, 4)
void attn_mfma_kernel(const float* __restrict__ Qw,
                      const ushort* __restrict__ KH, const ushort* __restrict__ KL,
                      const float* __restrict__ Vw, float* __restrict__ outp)
{
    // pool: [0,32768) Klds0|Klds1 (hist aliases after scores)
    //       [32768, 41472) Qs[32][68]   (sel aliases after scores)
    //       [41472, 58368) sc[32][132]
    __shared__ __align__(16) char pool[58368];
    __shared__ int2 piv[32];
    __shared__ int defc[32], bndc[32];
    __shared__ float rs_def[32], rs_bnd[32], rowsum[32];

    ushort* Klds0 = (ushort*)pool;
    ushort* Klds1 = Klds0 + 8192;
    int* hist = (int*)pool;                       // 128*33*4 = 16896 <= 32768
    float (*Qs)[68]  = (float(*)[68])(pool + 32768);
    float (*sc)[132] = (float(*)[132])(pool + 41472);
    uint2 (*sel)[MAXSEL] = (uint2(*)[MAXSEL])(pool + 32768);   // 32*76*8 = 19456 <= 25600

    const int t = threadIdx.x;
    const int bid0 = blockIdx.x;
    const int bid = (bid0 & 7) * 256 + (bid0 >> 3);   // XCD-bijective (2048 = 8*256)
    const int qt = bid & 31;
    const int bh = bid >> 5;
    const int n0 = qt * 32;
    const float* Qbase = Qw + ((size_t)bh * 1024 + n0) * 64;
    const float* Vbase = Vw + (size_t)bh * 1024 * 64;
    const ushort* KHb = KH + (size_t)bh * 1024 * 64;
    const ushort* KLb = KL + (size_t)bh * 1024 * 64;

    const int ll = t & 63;
    const int w  = t >> 6;               // 0..7
    const int qh = w >> 2;               // query half (16 rows each)
    const int kr = w & 3;                // key range (32 keys each)
    const int r  = t >> 4, l = t & 15;   // owner layout (32 rows)

    // stage Q tile (32x64 f32 = 8KB, one float4/thread)
    {
        int q = t >> 4, dq = (t & 15) * 4;
        *(float4*)&Qs[q][dq] = *(const float4*)(Qbase + q * 64 + dq);
    }
    // stage K chunk 0 via global_load_lds (linear dest, pre-swizzled source)
    auto stageK = [&](int c) {
        const size_t cb = (size_t)c * 8192;
        #pragma unroll
        for (int i = 0; i < 2; ++i) {
            int boff = i * 8192 + w * 1024;            // byte offset in 16KB buffer
            GLOAD_LDS16(KHb + cb + boff / 2 + ll * 8, ((char*)Klds0) + boff);
            GLOAD_LDS16(KLb + cb + boff / 2 + ll * 8, ((char*)Klds1) + boff);
        }
    };
    stageK(0);
    __syncthreads();

    // A fragments (Q 2-limb) for this wave's 16 query rows
    bf16x8_t aH[2], aL[2];
    {
        const int arow = qh * 16 + (ll & 15), akg = ll >> 4;
        #pragma unroll
        for (int s = 0; s < 2; ++s) {
            const float* qp = &Qs[arow][s*32 + akg*8];
            float4 q0 = *(const float4*)qp;
            float4 q1 = *(const float4*)(qp + 4);
            float qv[8] = {q0.x,q0.y,q0.z,q0.w,q1.x,q1.y,q1.z,q1.w};
            #pragma unroll
            for (int j = 0; j < 8; ++j) {
                ushort hh, lo2;
                limb2(qv[j], hh, lo2);
                aH[s][j] = (short)hh; aL[s][j] = (short)lo2;
            }
        }
    }
    __syncthreads();   // Qs reads done (sel aliases later); K chunk 0 landed

    unsigned ku[64];
    unsigned kumax = 0u;

    #pragma unroll
    for (int c = 0; c < 8; ++c) {
        // ---- scores: wave computes rows [qh*16,+16) x keys [kr*32,+32) ----
        #pragma unroll
        for (int tile = 0; tile < 2; ++tile) {
            const int m0 = kr * 32 + tile * 16;
            const int brow = m0 + (ll & 15);
            f32x4_t a_ = {0.f, 0.f, 0.f, 0.f};
            #pragma unroll
            for (int s = 0; s < 2; ++s) {
                int q2 = (s*4 + (ll >> 4)) ^ (brow & 7);
                int off = brow*64 + q2*8;
                bf16x8_t bH = *(const bf16x8_t*)&Klds0[off];
                bf16x8_t bL = *(const bf16x8_t*)&Klds1[off];
                a_ = __builtin_amdgcn_mfma_f32_16x16x32_bf16(aH[s], bH, a_, 0, 0, 0);
                a_ = __builtin_amdgcn_mfma_f32_16x16x32_bf16(aH[s], bL, a_, 0, 0, 0);
                a_ = __builtin_amdgcn_mfma_f32_16x16x32_bf16(aL[s], bH, a_, 0, 0, 0);
            }
            const int qr = qh * 16 + (ll >> 4) * 4;
            const int mcol = m0 + (ll & 15);
            sc[qr+0][mcol] = a_[0];
            sc[qr+1][mcol] = a_[1];
            sc[qr+2][mcol] = a_[2];
            sc[qr+3][mcol] = a_[3];
        }
        __syncthreads();

        // ---- issue next-chunk staging (async), then divergence-free pull ----
        if (c < 7) stageK(c + 1);
        {
            float4 v0 = *(const float4*)&sc[r][l*8];
            float4 v1 = *(const float4*)&sc[r][l*8 + 4];
            float vv[8] = {v0.x,v0.y,v0.z,v0.w,v1.x,v1.y,v1.z,v1.w};
            #pragma unroll
            for (int e = 0; e < 8; ++e) {
                float vc = fminf(fmaxf(vv[e], -31.9f), 31.9f);
                unsigned q = (unsigned)(int)fmaf(vc, 32768.f, 1048576.f);
                ku[c*8 + e] = q;
                kumax = (q > kumax) ? q : kumax;
            }
        }
        __syncthreads();   // staging landed + sc reads done
    }

    // row max across 16 lanes
    #pragma unroll
    for (int off = 8; off; off >>= 1) {
        unsigned o = __shfl_xor(kumax, off, 16);
        kumax = (o > kumax) ? o : kumax;
    }

    // zero selection counters (any thread order; barriers inside radix stages)
    if (t < 32) { defc[t] = 0; bndc[t] = 0; }

    // ---- exact 64th-largest via 3-stage 7-bit radix (bits [20:14],[13:7],[6:0]) ----
    int tgt = 64;
    radix_stage7(hist, r, l, ku, 0u, 0u, 14, tgt, piv);
    unsigned pref = (unsigned)piv[r].x << 14; tgt = piv[r].y;
    radix_stage7(hist, r, l, ku, pref, 0x1FC000u, 7, tgt, piv);
    pref |= (unsigned)piv[r].x << 7; tgt = piv[r].y;
    radix_stage7(hist, r, l, ku, pref, 0x1FFF80u, 0, tgt, piv);
    const unsigned thr = pref | (unsigned)piv[r].x;

    // ---- single-pass selection: band = thr +- 2 quanta; front = definite, back = boundary ----
    const unsigned bhi = thr + 2u;
    const unsigned blo = thr - 2u;                    // thr >= 3278, no underflow
    float lsd = 0.f, lsb = 0.f;
    #pragma unroll
    for (int j = 0; j < 64; ++j) {
        unsigned k = ku[j];
        if (k > bhi) {
            float wgt = __expf((float)(int)(k - kumax) * 3.814697265625e-6f);
            int slot = atomicAdd(&defc[r], 1);
            sel[r][slot] = make_uint2((unsigned)((j >> 3)*128 + l*8 + (j & 7)), __float_as_uint(wgt));
            lsd += wgt;
        } else if (k >= blo) {
            int bp = atomicAdd(&bndc[r], 1);
            int slot = (MAXSEL - 1) - bp;
            if (slot >= 64) {
                float wgt = __expf((float)(int)(k - kumax) * 3.814697265625e-6f);
                sel[r][slot] = make_uint2((unsigned)((j >> 3)*128 + l*8 + (j & 7)), __float_as_uint(wgt));
                lsb += wgt;
            }
        }
    }
    #pragma unroll
    for (int off = 8; off; off >>= 1) {
        lsd += __shfl_xor(lsd, off, 16);
        lsb += __shfl_xor(lsb, off, 16);
    }
    if (l == 0) { rs_def[r] = lsd; rs_bnd[r] = lsb; }
    __syncthreads();

    // ---- post-pass: apply frac to boundary entries, finalize rowsum ----
    if (t < 32) {
        int D = defc[t], m = bndc[t];
        float frac = (float)(64 - D) / (float)m;
        int mm = (m < MAXSEL - 64) ? m : (MAXSEL - 64);
        for (int i = 0; i < mm; ++i) {
            uint2 p = sel[t][(MAXSEL - 1) - i];
            p.y = __float_as_uint(__uint_as_float(p.y) * frac);
            sel[t][(MAXSEL - 1) - i] = p;
        }
        bndc[t] = mm;
        rowsum[t] = rs_def[t] + frac * rs_bnd[t];
    }
    __syncthreads();

    // ---- PV: thread = (row, d-quad); float4 V loads ----
    {
        const int pr = t >> 4;
        const int d4 = (t & 15) * 4;
        const int bb = bh >> 4, hh = bh & 15;
        const int D = defc[pr], m = bndc[pr];
        float4 a = make_float4(0.f, 0.f, 0.f, 0.f);
        for (int j = 0; j < D; ++j) {
            uint2 p = sel[pr][j];
            float wv = __uint_as_float(p.y);
            float4 v = *(const float4*)(Vbase + (size_t)p.x * 64 + d4);
            a.x += wv * v.x; a.y += wv * v.y; a.z += wv * v.z; a.w += wv * v.w;
        }
        for (int i = 0; i < m; ++i) {
            uint2 p = sel[pr][(MAXSEL - 1) - i];
            float wv = __uint_as_float(p.y);
            float4 v = *(const float4*)(Vbase + (size_t)p.x * 64 + d4);
            a.x += wv * v.x; a.y += wv * v.y; a.z += wv * v.z; a.w += wv * v.w;
        }
        float inv = 1.0f / rowsum[pr];
        a.x *= inv; a.y *= inv; a.z *= inv; a.w *= inv;
        *(float4*)(outp + ((size_t)bb * 1024 + (n0 + pr)) * 1024 + hh * 64 + d4) = a;
    }
}

extern "C" void kernel_launch(void* const* d_in, const int* in_sizes, int n_in,
                              void* d_out, int out_size, void* d_ws, size_t ws_size,
                              hipStream_t stream) {
    const float* x     = (const float*)d_in[0];
    const float* Wq    = (const float*)d_in[1];
    const float* bq    = (const float*)d_in[2];
    const float* Wk    = (const float*)d_in[3];
    const float* bk    = (const float*)d_in[4];
    const float* Wv    = (const float*)d_in[5];
    const float* bv    = (const float*)d_in[6];
    const float* Wo    = (const float*)d_in[7];
    const float* bo    = (const float*)d_in[8];
    const float* statk = (const float*)d_in[9];
    float* out = (float*)d_out;
    float* ws  = (float*)d_ws;

    const size_t NF = (size_t)1 << 22;

    float*  Qw  = ws;
    float*  Vw  = ws + NF;
    ushort* WL  = (ushort*)(ws + 2 * NF);
    float*  op  = ws + 2 * NF;           // aliases WL after GEMMs done
    ushort* KH  = (ushort*)(ws + 3 * NF);
    ushort* KL  = KH + NF;
    ushort* WoL = (ushort*)(ws + 4 * NF);

    dim3 gd(512, 4);
    decomp_w_kernel<<<gd, 256, 0, stream>>>(Wq, Wk, Wv, Wo, WL, WoL);

    dim3 g1(8, 32, 3);
    limb_gemm_kernel<<<g1, 256, 0, stream>>>(x, WL, WoL, bq, bk, bv, bo, statk,
                                             Qw, Vw, KH, KL, nullptr, 0);

    attn_mfma_kernel<<<2048, 512, 0, stream>>>(Qw, KH, KL, Vw, op);

    dim3 g2(8, 32, 1);
    limb_gemm_kernel<<<g2, 256, 0, stream>>>(op, WL, WoL, bq, bk, bv, bo, statk,
                                             Qw, Vw, KH, KL, out, 1);
}

// Round 8
// 302.493 us; speedup vs baseline: 3.3154x; 1.2919x over previous
//
#include <hip/hip_runtime.h>

#define NSTAT 32
#define MAXSEL 76

typedef __attribute__((ext_vector_type(8))) short bf16x8_t;
typedef __attribute__((ext_vector_type(4))) float f32x4_t;

#define GLOAD_LDS16(g, l) \
    __builtin_amdgcn_global_load_lds((const __attribute__((address_space(1))) void*)(g), \
                                     (__attribute__((address_space(3))) void*)(l), 16, 0, 0)

// round-to-nearest-even bf16
__device__ __forceinline__ ushort rtn_bf16(float a) {
    unsigned u = __float_as_uint(a);
    return (ushort)((u + 0x7FFFu + ((u >> 16) & 1u)) >> 16);
}
// 2-limb RTN decomposition: a ~= hi + lo, |residual| <= 2^-18 |a|
__device__ __forceinline__ void limb2(float a, ushort& h, ushort& l) {
    ushort hh = rtn_bf16(a);
    float fh = __uint_as_float(((unsigned)hh) << 16);
    float r1 = a - fh;
    l = rtn_bf16(r1);
    h = hh;
}

// ---------------- weight 2-limb decomposition (pre-swizzled tile layout) ----------------
// layout: flat = row*1024 + kt*32 + (q ^ (row&3))*8 + e
__global__ __launch_bounds__(256)
void decomp_w_kernel(const float* __restrict__ Wq, const float* __restrict__ Wk,
                     const float* __restrict__ Wv, const float* __restrict__ Wo,
                     ushort* __restrict__ WLq, ushort* __restrict__ WoLb)
{
    const int m = blockIdx.y;
    const float* src = (m == 0) ? Wq : (m == 1) ? Wk : (m == 2) ? Wv : Wo;
    const int idx = blockIdx.x * 256 + threadIdx.x;
    const int e8 = idx * 8;
    const int row = e8 >> 10, k0 = e8 & 1023;
    const int kt = k0 >> 5, q = (k0 >> 3) & 3;
    const size_t doff = ((size_t)row << 10) + (size_t)(kt * 32) + (size_t)((q ^ (row & 3)) * 8);

    float4 v0 = *(const float4*)(src + e8);
    float4 v1 = *(const float4*)(src + e8 + 4);
    float f[8] = {v0.x, v0.y, v0.z, v0.w, v1.x, v1.y, v1.z, v1.w};

    const size_t Mi = (size_t)1 << 20;
    ushort h[8], l[8];
    #pragma unroll
    for (int e = 0; e < 8; ++e) limb2(f[e], h[e], l[e]);
    ushort* H = (m == 3) ? WoLb : WLq + (size_t)(m * 2) * Mi;
    ushort* L = H + Mi;
    *(ushort4*)(H + doff)     = make_ushort4(h[0],h[1],h[2],h[3]);
    *(ushort4*)(H + doff + 4) = make_ushort4(h[4],h[5],h[6],h[7]);
    *(ushort4*)(L + doff)     = make_ushort4(l[0],l[1],l[2],l[3]);
    *(ushort4*)(L + doff + 4) = make_ushort4(l[4],l[5],l[6],l[7]);
}

// ---------------- 2-limb MFMA GEMM: C[128x128] = A[128,1024] @ W[128,1024]^T ----------------
// A fp32 decomposed on the fly (2-limb RTN); B pre-decomposed pre-swizzled bf16 2-limb.
// 3 products: aH*bH + aH*bL + aL*bH (drop aL*bL, rel err ~2^-18).
// mode: 0=Q (f32 out), 1=K (limb2 swizzled out + static keys), 2=V (f32 out), 3=OUT (f32 + bo)
__global__ __launch_bounds__(256, 3)
void limb_gemm_kernel(const float* __restrict__ A,
                      const ushort* __restrict__ WLq, const ushort* __restrict__ WoLb,
                      const float* __restrict__ bq, const float* __restrict__ bk,
                      const float* __restrict__ bv, const float* __restrict__ bo,
                      const float* __restrict__ statk,
                      float* __restrict__ Qw, float* __restrict__ Vw,
                      ushort* __restrict__ KHo, ushort* __restrict__ KLo,
                      float* __restrict__ Cout, int is_out)
{
    __shared__ __align__(16) ushort Al[2][128][32];
    __shared__ __align__(16) ushort Bl[2][2][128][32];

    const int t = threadIdx.x;
    const int bx = blockIdx.x, by = blockIdx.y;
    const int mode = is_out ? 3 : (int)blockIdx.z;
    const int wc0 = bx * 128;
    const int arow0 = by * 128;

    const size_t Mi = (size_t)1 << 20;
    const ushort* BpH;
    const float* bias;
    if (mode == 0)      { BpH = WLq;          bias = bq; }
    else if (mode == 1) { BpH = WLq + 2*Mi;   bias = bk; }
    else if (mode == 2) { BpH = WLq + 4*Mi;   bias = bv; }
    else                { BpH = WoLb;         bias = bo; }
    const ushort* BpL = BpH + Mi;

    const int ll = t & 63, w = t >> 6;

    f32x4_t acc[4][4];
    #pragma unroll
    for (int i = 0; i < 4; ++i)
        #pragma unroll
        for (int j = 0; j < 4; ++j) acc[i][j] = (f32x4_t){0.f, 0.f, 0.f, 0.f};

    // B: global_load_lds, pre-swizzled source, linear LDS dest (8KB/limb = 8 wave-calls of 1KB)
    auto stageB = [&](int kt, int bb) {
        #pragma unroll
        for (int limb = 0; limb < 2; ++limb) {
            const ushort* src = limb ? BpL : BpH;
            #pragma unroll
            for (int call = 0; call < 2; ++call) {
                int chunk = (w * 2 + call) * 64 + ll;
                int eoff = chunk * 8;
                int row = eoff >> 5, qp = (eoff >> 3) & 3;
                const ushort* g = src + ((size_t)(wc0 + row) << 10) + kt * 32 + qp * 8;
                char* l = ((char*)&Bl[bb][limb][0][0]) + (w * 2 + call) * 1024;
                GLOAD_LDS16(g, l);
            }
        }
    };
    const int srow = t >> 1, skh = (t & 1) * 16;
    auto loadA = [&](int kt, float4* a4) {
        const float* p = A + (((size_t)(arow0 + srow)) << 10) + kt * 32 + skh;
        a4[0] = *(const float4*)(p + 0);
        a4[1] = *(const float4*)(p + 4);
        a4[2] = *(const float4*)(p + 8);
        a4[3] = *(const float4*)(p + 12);
    };
    auto writeA = [&](const float4* a4) {
        float f[16];
        #pragma unroll
        for (int i = 0; i < 4; ++i) {
            f[i*4+0] = a4[i].x; f[i*4+1] = a4[i].y; f[i*4+2] = a4[i].z; f[i*4+3] = a4[i].w;
        }
        ushort h[16], lo[16];
        #pragma unroll
        for (int e = 0; e < 16; ++e) limb2(f[e], h[e], lo[e]);
        const int sw = srow & 3;
        #pragma unroll
        for (int qq = 0; qq < 2; ++qq) {
            int q = (skh >> 3) + qq;
            int qo = (q ^ sw) * 8;
            bf16x8_t vH, vL;
            #pragma unroll
            for (int e = 0; e < 8; ++e) {
                vH[e] = (short)h[qq*8+e]; vL[e] = (short)lo[qq*8+e];
            }
            *(bf16x8_t*)&Al[0][srow][qo] = vH;
            *(bf16x8_t*)&Al[1][srow][qo] = vL;
        }
    };

    const int wr = (w >> 1) * 64, wcv = (w & 1) * 64;
    const int fr = ll & 15, kg = ll >> 4;

    auto compute = [&](int bb) {
        bf16x8_t af[4][2];
        #pragma unroll
        for (int i = 0; i < 4; ++i) {
            int row = wr + i * 16 + fr;
            int qo = (kg ^ (row & 3)) * 8;
            af[i][0] = *(const bf16x8_t*)&Al[0][row][qo];
            af[i][1] = *(const bf16x8_t*)&Al[1][row][qo];
        }
        #pragma unroll
        for (int j = 0; j < 4; ++j) {
            int row = wcv + j * 16 + fr;
            int qo = (kg ^ (row & 3)) * 8;
            bf16x8_t b0 = *(const bf16x8_t*)&Bl[bb][0][row][qo];
            bf16x8_t b1 = *(const bf16x8_t*)&Bl[bb][1][row][qo];
            #pragma unroll
            for (int i = 0; i < 4; ++i) {
                acc[i][j] = __builtin_amdgcn_mfma_f32_16x16x32_bf16(af[i][0], b0, acc[i][j], 0, 0, 0);
                acc[i][j] = __builtin_amdgcn_mfma_f32_16x16x32_bf16(af[i][0], b1, acc[i][j], 0, 0, 0);
                acc[i][j] = __builtin_amdgcn_mfma_f32_16x16x32_bf16(af[i][1], b0, acc[i][j], 0, 0, 0);
            }
        }
    };

    float4 a4[4];
    loadA(0, a4);
    writeA(a4);
    stageB(0, 0);
    __syncthreads();

    float4 a4n[4];
    for (int kt = 0; kt < 32; ++kt) {
        int bb = kt & 1;
        if (kt < 31) {
            stageB(kt + 1, bb ^ 1);
            loadA(kt + 1, a4n);
        }
        compute(bb);
        __syncthreads();
        if (kt < 31) writeA(a4n);
        __syncthreads();
    }

    #pragma unroll
    for (int i = 0; i < 4; ++i) {
        #pragma unroll
        for (int j = 0; j < 4; ++j) {
            int c = wc0 + wcv + j * 16 + (ll & 15);
            float bv_ = bias[c];
            #pragma unroll
            for (int q = 0; q < 4; ++q) {
                int gr = arow0 + wr + i * 16 + (kg) * 4 + q;
                float v = acc[i][j][q] + bv_;
                if (mode == 3) {
                    Cout[(size_t)gr * 1024 + c] = v;
                } else {
                    int b = gr >> 10, n = gr & 1023;
                    int h = c >> 6, d = c & 63;
                    size_t bhn = ((size_t)(b * 16 + h)) * 1024 + n;
                    if (mode == 1) {
                        if (n < NSTAT) v = statk[n * 1024 + c];
                        ushort kh, klo;
                        limb2(v, kh, klo);
                        size_t off = bhn * 64 + (size_t)(((d >> 3) ^ (n & 7)) * 8) + (d & 7);
                        KHo[off] = kh;
                        KLo[off] = klo;
                    } else {
                        float* Out = (mode == 0) ? Qw : Vw;
                        Out[bhn * 64 + d] = v;
                    }
                }
            }
        }
    }
}

// ---------------- radix-select stage, 7-bit bins, padded hist[bin*33 + r] ----------------
__device__ __forceinline__ void radix_stage7(int* __restrict__ hist, int r, int l,
                                             const unsigned* __restrict__ ku,
                                             unsigned pref, unsigned mask, int shift,
                                             int tgt, int2* __restrict__ piv)
{
    #pragma unroll
    for (int b = 0; b < 8; ++b) hist[(l*8 + b)*33 + r] = 0;
    __syncthreads();
    #pragma unroll
    for (int j = 0; j < 64; ++j) {
        unsigned k = ku[j];
        if ((k & mask) == pref)
            atomicAdd(&hist[(int)((k >> shift) & 127u)*33 + r], 1);
    }
    __syncthreads();
    int seg = 0;
    #pragma unroll
    for (int b = 0; b < 8; ++b) seg += hist[(l*8 + b)*33 + r];
    int suf = seg;
    #pragma unroll
    for (int off = 1; off < 16; off <<= 1) {
        int v = __shfl_down(suf, off, 16);
        suf += (l + off < 16) ? v : 0;
    }
    const int above = suf - seg;
    if (above < tgt && above + seg >= tgt) {
        int c = above;
        #pragma unroll
        for (int b = 7; b >= 0; --b) {
            int h = hist[(l*8 + b)*33 + r];
            if (c + h >= tgt) { piv[r] = make_int2(l*8 + b, tgt - c); break; }
            c += h;
        }
    }
    __syncthreads();
}

// ---------------- MFMA attn (unchanged from R7, validated) ----------------
__global__ __launch_bounds__(512, 4)
void attn_mfma_kernel(const float* __restrict__ Qw,
                      const ushort* __restrict__ KH, const ushort* __restrict__ KL,
                      const float* __restrict__ Vw, float* __restrict__ outp)
{
    __shared__ __align__(16) char pool[58368];
    __shared__ int2 piv[32];
    __shared__ int defc[32], bndc[32];
    __shared__ float rs_def[32], rs_bnd[32], rowsum[32];

    ushort* Klds0 = (ushort*)pool;
    ushort* Klds1 = Klds0 + 8192;
    int* hist = (int*)pool;
    float (*Qs)[68]  = (float(*)[68])(pool + 32768);
    float (*sc)[132] = (float(*)[132])(pool + 41472);
    uint2 (*sel)[MAXSEL] = (uint2(*)[MAXSEL])(pool + 32768);

    const int t = threadIdx.x;
    const int bid0 = blockIdx.x;
    const int bid = (bid0 & 7) * 256 + (bid0 >> 3);
    const int qt = bid & 31;
    const int bh = bid >> 5;
    const int n0 = qt * 32;
    const float* Qbase = Qw + ((size_t)bh * 1024 + n0) * 64;
    const float* Vbase = Vw + (size_t)bh * 1024 * 64;
    const ushort* KHb = KH + (size_t)bh * 1024 * 64;
    const ushort* KLb = KL + (size_t)bh * 1024 * 64;

    const int ll = t & 63;
    const int w  = t >> 6;
    const int qh = w >> 2;
    const int kr = w & 3;
    const int r  = t >> 4, l = t & 15;

    {
        int q = t >> 4, dq = (t & 15) * 4;
        *(float4*)&Qs[q][dq] = *(const float4*)(Qbase + q * 64 + dq);
    }
    auto stageK = [&](int c) {
        const size_t cb = (size_t)c * 8192;
        #pragma unroll
        for (int i = 0; i < 2; ++i) {
            int boff = i * 8192 + w * 1024;
            GLOAD_LDS16(KHb + cb + boff / 2 + ll * 8, ((char*)Klds0) + boff);
            GLOAD_LDS16(KLb + cb + boff / 2 + ll * 8, ((char*)Klds1) + boff);
        }
    };
    stageK(0);
    __syncthreads();

    bf16x8_t aH[2], aL[2];
    {
        const int arow = qh * 16 + (ll & 15), akg = ll >> 4;
        #pragma unroll
        for (int s = 0; s < 2; ++s) {
            const float* qp = &Qs[arow][s*32 + akg*8];
            float4 q0 = *(const float4*)qp;
            float4 q1 = *(const float4*)(qp + 4);
            float qv[8] = {q0.x,q0.y,q0.z,q0.w,q1.x,q1.y,q1.z,q1.w};
            #pragma unroll
            for (int j = 0; j < 8; ++j) {
                ushort hh, lo2;
                limb2(qv[j], hh, lo2);
                aH[s][j] = (short)hh; aL[s][j] = (short)lo2;
            }
        }
    }
    __syncthreads();

    unsigned ku[64];
    unsigned kumax = 0u;

    #pragma unroll
    for (int c = 0; c < 8; ++c) {
        #pragma unroll
        for (int tile = 0; tile < 2; ++tile) {
            const int m0 = kr * 32 + tile * 16;
            const int brow = m0 + (ll & 15);
            f32x4_t a_ = {0.f, 0.f, 0.f, 0.f};
            #pragma unroll
            for (int s = 0; s < 2; ++s) {
                int q2 = (s*4 + (ll >> 4)) ^ (brow & 7);
                int off = brow*64 + q2*8;
                bf16x8_t bH = *(const bf16x8_t*)&Klds0[off];
                bf16x8_t bL = *(const bf16x8_t*)&Klds1[off];
                a_ = __builtin_amdgcn_mfma_f32_16x16x32_bf16(aH[s], bH, a_, 0, 0, 0);
                a_ = __builtin_amdgcn_mfma_f32_16x16x32_bf16(aH[s], bL, a_, 0, 0, 0);
                a_ = __builtin_amdgcn_mfma_f32_16x16x32_bf16(aL[s], bH, a_, 0, 0, 0);
            }
            const int qr = qh * 16 + (ll >> 4) * 4;
            const int mcol = m0 + (ll & 15);
            sc[qr+0][mcol] = a_[0];
            sc[qr+1][mcol] = a_[1];
            sc[qr+2][mcol] = a_[2];
            sc[qr+3][mcol] = a_[3];
        }
        __syncthreads();

        if (c < 7) stageK(c + 1);
        {
            float4 v0 = *(const float4*)&sc[r][l*8];
            float4 v1 = *(const float4*)&sc[r][l*8 + 4];
            float vv[8] = {v0.x,v0.y,v0.z,v0.w,v1.x,v1.y,v1.z,v1.w};
            #pragma unroll
            for (int e = 0; e < 8; ++e) {
                float vc = fminf(fmaxf(vv[e], -31.9f), 31.9f);
                unsigned q = (unsigned)(int)fmaf(vc, 32768.f, 1048576.f);
                ku[c*8 + e] = q;
                kumax = (q > kumax) ? q : kumax;
            }
        }
        __syncthreads();
    }

    #pragma unroll
    for (int off = 8; off; off >>= 1) {
        unsigned o = __shfl_xor(kumax, off, 16);
        kumax = (o > kumax) ? o : kumax;
    }

    if (t < 32) { defc[t] = 0; bndc[t] = 0; }

    int tgt = 64;
    radix_stage7(hist, r, l, ku, 0u, 0u, 14, tgt, piv);
    unsigned pref = (unsigned)piv[r].x << 14; tgt = piv[r].y;
    radix_stage7(hist, r, l, ku, pref, 0x1FC000u, 7, tgt, piv);
    pref |= (unsigned)piv[r].x << 7; tgt = piv[r].y;
    radix_stage7(hist, r, l, ku, pref, 0x1FFF80u, 0, tgt, piv);
    const unsigned thr = pref | (unsigned)piv[r].x;

    const unsigned bhi = thr + 2u;
    const unsigned blo = thr - 2u;
    float lsd = 0.f, lsb = 0.f;
    #pragma unroll
    for (int j = 0; j < 64; ++j) {
        unsigned k = ku[j];
        if (k > bhi) {
            float wgt = __expf((float)(int)(k - kumax) * 3.814697265625e-6f);
            int slot = atomicAdd(&defc[r], 1);
            sel[r][slot] = make_uint2((unsigned)((j >> 3)*128 + l*8 + (j & 7)), __float_as_uint(wgt));
            lsd += wgt;
        } else if (k >= blo) {
            int bp = atomicAdd(&bndc[r], 1);
            int slot = (MAXSEL - 1) - bp;
            if (slot >= 64) {
                float wgt = __expf((float)(int)(k - kumax) * 3.814697265625e-6f);
                sel[r][slot] = make_uint2((unsigned)((j >> 3)*128 + l*8 + (j & 7)), __float_as_uint(wgt));
                lsb += wgt;
            }
        }
    }
    #pragma unroll
    for (int off = 8; off; off >>= 1) {
        lsd += __shfl_xor(lsd, off, 16);
        lsb += __shfl_xor(lsb, off, 16);
    }
    if (l == 0) { rs_def[r] = lsd; rs_bnd[r] = lsb; }
    __syncthreads();

    if (t < 32) {
        int D = defc[t], m = bndc[t];
        float frac = (float)(64 - D) / (float)m;
        int mm = (m < MAXSEL - 64) ? m : (MAXSEL - 64);
        for (int i = 0; i < mm; ++i) {
            uint2 p = sel[t][(MAXSEL - 1) - i];
            p.y = __float_as_uint(__uint_as_float(p.y) * frac);
            sel[t][(MAXSEL - 1) - i] = p;
        }
        bndc[t] = mm;
        rowsum[t] = rs_def[t] + frac * rs_bnd[t];
    }
    __syncthreads();

    {
        const int pr = t >> 4;
        const int d4 = (t & 15) * 4;
        const int bb = bh >> 4, hh = bh & 15;
        const int D = defc[pr], m = bndc[pr];
        float4 a = make_float4(0.f, 0.f, 0.f, 0.f);
        for (int j = 0; j < D; ++j) {
            uint2 p = sel[pr][j];
            float wv = __uint_as_float(p.y);
            float4 v = *(const float4*)(Vbase + (size_t)p.x * 64 + d4);
            a.x += wv * v.x; a.y += wv * v.y; a.z += wv * v.z; a.w += wv * v.w;
        }
        for (int i = 0; i < m; ++i) {
            uint2 p = sel[pr][(MAXSEL - 1) - i];
            float wv = __uint_as_float(p.y);
            float4 v = *(const float4*)(Vbase + (size_t)p.x * 64 + d4);
            a.x += wv * v.x; a.y += wv * v.y; a.z += wv * v.z; a.w += wv * v.w;
        }
        float inv = 1.0f / rowsum[pr];
        a.x *= inv; a.y *= inv; a.z *= inv; a.w *= inv;
        *(float4*)(outp + ((size_t)bb * 1024 + (n0 + pr)) * 1024 + hh * 64 + d4) = a;
    }
}

extern "C" void kernel_launch(void* const* d_in, const int* in_sizes, int n_in,
                              void* d_out, int out_size, void* d_ws, size_t ws_size,
                              hipStream_t stream) {
    const float* x     = (const float*)d_in[0];
    const float* Wq    = (const float*)d_in[1];
    const float* bq    = (const float*)d_in[2];
    const float* Wk    = (const float*)d_in[3];
    const float* bk    = (const float*)d_in[4];
    const float* Wv    = (const float*)d_in[5];
    const float* bv    = (const float*)d_in[6];
    const float* Wo    = (const float*)d_in[7];
    const float* bo    = (const float*)d_in[8];
    const float* statk = (const float*)d_in[9];
    float* out = (float*)d_out;
    char* base = (char*)d_ws;

    const size_t MiB = (size_t)1 << 20;
    // layout (ws >= 72 MiB proven):
    // [0,16)   Qw f32
    // [16,32)  Vw f32
    // [32,40)  KH  [40,48) KL
    // [48,52)  Wo 2-limb (WoH, WoL)
    // [52,64)  W-qkv 2-limb (6 x 2MiB); op f32 [52,68) aliases it after GEMMs
    float*  Qw   = (float*)(base);
    float*  Vw   = (float*)(base + 16*MiB);
    ushort* KH   = (ushort*)(base + 32*MiB);
    ushort* KL   = (ushort*)(base + 40*MiB);
    ushort* WoLb = (ushort*)(base + 48*MiB);
    ushort* WLq  = (ushort*)(base + 52*MiB);
    float*  op   = (float*)(base + 52*MiB);

    dim3 gd(512, 4);
    decomp_w_kernel<<<gd, 256, 0, stream>>>(Wq, Wk, Wv, Wo, WLq, WoLb);

    dim3 g1(8, 32, 3);
    limb_gemm_kernel<<<g1, 256, 0, stream>>>(x, WLq, WoLb, bq, bk, bv, bo, statk,
                                             Qw, Vw, KH, KL, nullptr, 0);

    attn_mfma_kernel<<<2048, 512, 0, stream>>>(Qw, KH, KL, Vw, op);

    dim3 g2(8, 32, 1);
    limb_gemm_kernel<<<g2, 256, 0, stream>>>(op, WLq, WoLb, bq, bk, bv, bo, statk,
                                             Qw, Vw, KH, KL, out, 1);
}